// Round 2
// baseline (308.076 us; speedup 1.0000x reference)
//
#include <hip/hip_runtime.h>
#include <hip/hip_bf16.h>

typedef __hip_bfloat16 bf16;
typedef __attribute__((ext_vector_type(4))) float f32x4;
typedef __attribute__((ext_vector_type(8))) short s16x8;

#define MFMA(a, b, c) __builtin_amdgcn_mfma_f32_16x16x32_bf16((a), (b), (c), 0, 0, 0)

__device__ __forceinline__ void g2l16(const bf16* g, bf16* l) {
  __builtin_amdgcn_global_load_lds((const __attribute__((address_space(1))) void*)g,
                                   (__attribute__((address_space(3))) void*)l,
                                   16, 0, 0);
}
__device__ __forceinline__ bf16 cvt_bf(float f) { return __float2bfloat16(f); }

// ---------------------------------------------------------------------------
// Weight transpose + f32->bf16:  W[K][N] f32  ->  Wt[N][K] bf16
// ---------------------------------------------------------------------------
__global__ __launch_bounds__(256)
void wcvt_k(const float* __restrict__ W, bf16* __restrict__ Wt, int K, int N)
{
  __shared__ float tl[32][33];
  const int n0 = blockIdx.x * 32, k0 = blockIdx.y * 32;
  const int tx = threadIdx.x & 31, ty = threadIdx.x >> 5;  // ty 0..7
#pragma unroll
  for (int i = 0; i < 32; i += 8)
    tl[ty + i][tx] = W[(size_t)(k0 + ty + i) * N + n0 + tx];
  __syncthreads();
#pragma unroll
  for (int i = 0; i < 32; i += 8)
    Wt[(size_t)(n0 + ty + i) * K + k0 + tx] = cvt_bf(tl[tx][ty + i]);
}

// ---------------------------------------------------------------------------
// query f32 -> bf16 (8 elements / thread)
// ---------------------------------------------------------------------------
__global__ __launch_bounds__(256)
void cvt_k(const float* __restrict__ in, bf16* __restrict__ o)
{
  const int i = (blockIdx.x * 256 + threadIdx.x) * 8;
  float4 a = *(const float4*)(in + i);
  float4 b = *(const float4*)(in + i + 4);
  union { bf16 h[8]; s16x8 v; } u;
  u.h[0] = cvt_bf(a.x); u.h[1] = cvt_bf(a.y); u.h[2] = cvt_bf(a.z); u.h[3] = cvt_bf(a.w);
  u.h[4] = cvt_bf(b.x); u.h[5] = cvt_bf(b.y); u.h[6] = cvt_bf(b.z); u.h[7] = cvt_bf(b.w);
  *(s16x8*)(o + i) = u.v;
}

// ---------------------------------------------------------------------------
// GEMM: C[M][N] = A[M][K] @ Bt[N][K]^T (+bias) (+resid) (relu)
// EPI 0: bf16 out + bias                 (QKV)
// EPI 1: f32 out + bias + f32 residual   (out-proj, FFN2)
// EPI 2: bf16 out + bias + relu          (FFN1)
// 128x128 tile, BK=64, 4 waves (2x2 of 64x64), 16x16x32 MFMA.
// LDS tiles XOR-swizzled: LDS[r][chunk c] = global chunk (c ^ (r&7)); reads
// apply the same involution (both-sides rule, guide rule #21).
// ---------------------------------------------------------------------------
template<int EPI>
__global__ __launch_bounds__(256, 2)
void gemm_k(const bf16* __restrict__ A, const bf16* __restrict__ Bt,
            const float* __restrict__ bias, const float* __restrict__ resid,
            bf16* __restrict__ Cb, float* __restrict__ Cf,
            int M, int N, int K)
{
  __shared__ bf16 As[128 * 64];
  __shared__ bf16 Bs[128 * 64];
  const int tid = threadIdx.x;
  const int wave = tid >> 6, lane = tid & 63;
  const int m0 = blockIdx.x * 128, n0 = blockIdx.y * 128;
  const int wm = (wave >> 1) * 64, wn = (wave & 1) * 64;
  const int srl = lane >> 3;                                  // staging sub-row 0..7
  const int csub = ((lane & 7) ^ ((lane >> 3) & 7)) * 8;      // swizzled source chunk (elems)

  f32x4 acc[4][4];
#pragma unroll
  for (int i = 0; i < 4; ++i)
#pragma unroll
    for (int j = 0; j < 4; ++j) acc[i][j] = (f32x4)0.f;

  for (int k0 = 0; k0 < K; k0 += 64) {
#pragma unroll
    for (int is = 0; is < 4; ++is) {
      const int tr = wave * 32 + is * 8;  // tile row base (wave-uniform)
      g2l16(A  + (size_t)(m0 + tr + srl) * K + (k0 + csub), As + tr * 64);
      g2l16(Bt + (size_t)(n0 + tr + srl) * K + (k0 + csub), Bs + tr * 64);
    }
    __syncthreads();
#pragma unroll
    for (int ks = 0; ks < 2; ++ks) {
      s16x8 af[4], bfr[4];
#pragma unroll
      for (int i = 0; i < 4; ++i) {
        const int ar = wm + i * 16 + (lane & 15);
        af[i]  = *(const s16x8*)((const char*)As + ar * 128 + ((ks * 4 + (lane >> 4)) ^ (ar & 7)) * 16);
        const int br = wn + i * 16 + (lane & 15);
        bfr[i] = *(const s16x8*)((const char*)Bs + br * 128 + ((ks * 4 + (lane >> 4)) ^ (br & 7)) * 16);
      }
#pragma unroll
      for (int mi = 0; mi < 4; ++mi)
#pragma unroll
        for (int ni = 0; ni < 4; ++ni)
          acc[mi][ni] = MFMA(af[mi], bfr[ni], acc[mi][ni]);
    }
    __syncthreads();
  }

#pragma unroll
  for (int ni = 0; ni < 4; ++ni) {
    const int col = n0 + wn + ni * 16 + (lane & 15);
    const float bv = bias[col];
#pragma unroll
    for (int mi = 0; mi < 4; ++mi) {
#pragma unroll
      for (int r = 0; r < 4; ++r) {
        const int row = m0 + wm + mi * 16 + (lane >> 4) * 4 + r;
        float v = acc[mi][ni][r] + bv;
        if constexpr (EPI == 1) v += resid[(size_t)row * N + col];
        if constexpr (EPI == 2) v = fmaxf(v, 0.f);
        if constexpr (EPI == 1) Cf[(size_t)row * N + col] = v;
        else                    Cb[(size_t)row * N + col] = cvt_bf(v);
      }
    }
  }
}

// ---------------------------------------------------------------------------
// V transpose: V (per-bh [1024 k][64 d]) -> Vt per-bh [64 d][1024 k]
// ---------------------------------------------------------------------------
__global__ __launch_bounds__(256)
void vtr_k(const bf16* __restrict__ V, bf16* __restrict__ Vt)
{
  __shared__ bf16 tl[64][72];
  const int bh = blockIdx.y, kt = blockIdx.x;
  const int r = threadIdx.x >> 2, c = threadIdx.x & 3;
  const bf16* src = V + (size_t)bh * 65536 + (size_t)(kt * 64 + r) * 64 + c * 16;
  *(s16x8*)&tl[r][c * 16]     = *(const s16x8*)(src);
  *(s16x8*)&tl[r][c * 16 + 8] = *(const s16x8*)(src + 8);
  __syncthreads();
  union { bf16 h[8]; s16x8 v; } u0, u1;
#pragma unroll
  for (int j = 0; j < 8; ++j) { u0.h[j] = tl[c * 16 + j][r]; u1.h[j] = tl[c * 16 + 8 + j][r]; }
  bf16* dst = Vt + (size_t)bh * 65536 + (size_t)r * 1024 + kt * 64 + c * 16;
  *(s16x8*)dst = u0.v;
  *(s16x8*)(dst + 8) = u1.v;
}

// ---------------------------------------------------------------------------
// Attention: per (bh, 64 q-rows). ctx = (exp(QK^T/8)*mask) @ V / max(rowsum,1)
// 4 waves x 16 q-rows. K tile 32x64 (swizzled LDS), Vt tile 64x32, per-wave P.
// Rowsum via MFMA with all-ones B: lands in same layout as ctx accumulator.
// ---------------------------------------------------------------------------
__global__ __launch_bounds__(256, 2)
void attn_k(const bf16* __restrict__ Q, const bf16* __restrict__ Kp,
            const bf16* __restrict__ Vt, const int* __restrict__ mask,
            bf16* __restrict__ ctx)
{
  __shared__ bf16 Ks[32 * 64];
  __shared__ bf16 Vs[64 * 32];
  __shared__ bf16 Ps[4][16 * 32];
  const int lane = threadIdx.x & 63, wave = threadIdx.x >> 6;
  const int bh = blockIdx.y;
  const int q0 = blockIdx.x * 64 + wave * 16;
  const bf16* Qg = Q  + (size_t)bh * 65536;
  const bf16* Kg = Kp + (size_t)bh * 65536;
  const bf16* Vg = Vt + (size_t)bh * 65536;
  const int* mrow = mask + (bh & 7) * 1024;   // torch tile(nheads,1): row bh % B

  const s16x8 qa0 = *(const s16x8*)(Qg + (size_t)(q0 + (lane & 15)) * 64 + (lane >> 4) * 8);
  const s16x8 qa1 = *(const s16x8*)(Qg + (size_t)(q0 + (lane & 15)) * 64 + 32 + (lane >> 4) * 8);
  int mq[4];
#pragma unroll
  for (int r = 0; r < 4; ++r) mq[r] = mrow[q0 + (lane >> 4) * 4 + r];

  s16x8 ones;
#pragma unroll
  for (int i = 0; i < 8; ++i) ones[i] = (short)0x3F80;  // bf16 1.0

  f32x4 actx[4];
#pragma unroll
  for (int i = 0; i < 4; ++i) actx[i] = (f32x4)0.f;
  f32x4 asum = (f32x4)0.f;

  const int csubK = ((lane & 7) ^ ((lane >> 3) & 7)) * 8;

  for (int kt = 0; kt < 32; ++kt) {
    // stage K tile (32 rows x 64 dh), swizzled; each wave: 8 rows
    g2l16(Kg + (size_t)(kt * 32 + wave * 8 + (lane >> 3)) * 64 + csubK, Ks + wave * 8 * 64);
    // stage Vt tile (64 d x 32 k), linear; each wave: 16 d-rows
    g2l16(Vg + (size_t)(wave * 16 + (lane >> 2)) * 1024 + kt * 32 + (lane & 3) * 8,
          Vs + wave * 16 * 32);
    __syncthreads();

#pragma unroll
    for (int kb = 0; kb < 2; ++kb) {
      const int krow = kb * 16 + (lane & 15);
      s16x8 kf0 = *(const s16x8*)((const char*)Ks + krow * 128 + (((lane >> 4)    ) ^ (krow & 7)) * 16);
      s16x8 kf1 = *(const s16x8*)((const char*)Ks + krow * 128 + (((lane >> 4) + 4) ^ (krow & 7)) * 16);
      f32x4 z = (f32x4)0.f;
      z = MFMA(qa0, kf0, z);
      z = MFMA(qa1, kf1, z);
      const int mk = mrow[kt * 32 + kb * 16 + (lane & 15)];
#pragma unroll
      for (int r = 0; r < 4; ++r) {
        const float e = (mk && mq[r]) ? __expf(z[r] * 0.125f) : 0.f;
        Ps[wave][((lane >> 4) * 4 + r) * 32 + kb * 16 + (lane & 15)] = cvt_bf(e);
      }
    }
    __syncthreads();

    const s16x8 pa = *(const s16x8*)((const char*)&Ps[wave][0] + (lane & 15) * 64 + (lane >> 4) * 16);
#pragma unroll
    for (int db = 0; db < 4; ++db) {
      const s16x8 vf = *(const s16x8*)((const char*)Vs + (db * 16 + (lane & 15)) * 64 + (lane >> 4) * 16);
      actx[db] = MFMA(pa, vf, actx[db]);
    }
    asum = MFMA(pa, ones, asum);
    __syncthreads();
  }

#pragma unroll
  for (int r = 0; r < 4; ++r) {
    const float inv = 1.f / fmaxf(asum[r], 1.f);
    const int qr = q0 + (lane >> 4) * 4 + r;
#pragma unroll
    for (int db = 0; db < 4; ++db)
      ctx[(size_t)bh * 65536 + (size_t)qr * 64 + db * 16 + (lane & 15)] = cvt_bf(actx[db][r] * inv);
  }
}

// ---------------------------------------------------------------------------
// LayerNorm over D=512. 1 wave / row, 4 rows / block. Optional bf16 copy out.
// Safe to run in-place (of == x): each thread reads/writes only its own 8.
// ---------------------------------------------------------------------------
template<int WB16>
__global__ __launch_bounds__(256)
void ln_k(const float* __restrict__ x, const float* __restrict__ g,
          const float* __restrict__ bb, float* __restrict__ of, bf16* __restrict__ ob)
{
  const int row = blockIdx.x * 4 + (threadIdx.x >> 6);
  const int lane = threadIdx.x & 63;
  const float* xr = x + (size_t)row * 512 + lane * 8;
  float4 a = *(const float4*)xr;
  float4 b = *(const float4*)(xr + 4);
  float xv[8] = {a.x, a.y, a.z, a.w, b.x, b.y, b.z, b.w};
  float s = 0.f, q = 0.f;
#pragma unroll
  for (int j = 0; j < 8; ++j) { s += xv[j]; q += xv[j] * xv[j]; }
#pragma unroll
  for (int m = 1; m < 64; m <<= 1) { s += __shfl_xor(s, m); q += __shfl_xor(q, m); }
  const float mu = s * (1.f / 512.f);
  const float var = q * (1.f / 512.f) - mu * mu;
  const float rs = rsqrtf(var + 1e-5f);
  float4 g0 = *(const float4*)(g + lane * 8),  g1 = *(const float4*)(g + lane * 8 + 4);
  float4 b0 = *(const float4*)(bb + lane * 8), b1 = *(const float4*)(bb + lane * 8 + 4);
  float gv[8] = {g0.x, g0.y, g0.z, g0.w, g1.x, g1.y, g1.z, g1.w};
  float bv[8] = {b0.x, b0.y, b0.z, b0.w, b1.x, b1.y, b1.z, b1.w};
  float ov[8];
#pragma unroll
  for (int j = 0; j < 8; ++j) ov[j] = (xv[j] - mu) * rs * gv[j] + bv[j];
  float4 o0 = {ov[0], ov[1], ov[2], ov[3]};
  float4 o1 = {ov[4], ov[5], ov[6], ov[7]};
  float* outr = of + (size_t)row * 512 + lane * 8;
  *(float4*)outr = o0;
  *(float4*)(outr + 4) = o1;
  if constexpr (WB16) {
    union { bf16 h[8]; s16x8 v; } u;
#pragma unroll
    for (int j = 0; j < 8; ++j) u.h[j] = cvt_bf(ov[j]);
    *(s16x8*)(ob + (size_t)row * 512 + lane * 8) = u.v;
  }
}

// ---------------------------------------------------------------------------
// mask -> f32 into both mask output slots
// ---------------------------------------------------------------------------
__global__ __launch_bounds__(256)
void mask_k(const int* __restrict__ m, float* __restrict__ out)
{
  const int i = blockIdx.x * 256 + threadIdx.x;  // 8192 total
  const float v = (float)m[i];
  out[4194304 + i] = v;
  out[12591104 + i] = v;
}

// ---------------------------------------------------------------------------
// Scratch plan: everything except the 4 MB of bf16 weight buffers lives in
// d_out regions that are dead until the final writes:
//   R0 = out2 slot      [byte 0, 16.77MB):      qb -> ctx -> x1b -> ybuf (LN2 in-place)
//   R1 = query-copy #1  [byte 16,809,984, +16.77MB): Q+K -> attnres -> hbuf
//   R2 = query-copy #2  [byte 33,587,200, +16.77MB): V+Vt -> x1f
// Final mask_k / memcpys overwrite R1/R2/mask slots last (stream-ordered).
// ---------------------------------------------------------------------------
extern "C" void kernel_launch(void* const* d_in, const int* in_sizes, int n_in,
                              void* d_out, int out_size, void* d_ws, size_t ws_size,
                              hipStream_t stream)
{
  const float* query = (const float*)d_in[0];
  const int*   qmask = (const int*)d_in[1];
  const float* wq = (const float*)d_in[2];
  const float* bq = (const float*)d_in[3];
  const float* wk = (const float*)d_in[4];
  const float* bk = (const float*)d_in[5];
  const float* wv = (const float*)d_in[6];
  const float* bv = (const float*)d_in[7];
  const float* wo = (const float*)d_in[8];
  const float* bo = (const float*)d_in[9];
  const float* ln1g = (const float*)d_in[10];
  const float* ln1b = (const float*)d_in[11];
  const float* w1 = (const float*)d_in[12];
  const float* b1 = (const float*)d_in[13];
  const float* w2 = (const float*)d_in[14];
  const float* b2 = (const float*)d_in[15];
  const float* ln2g = (const float*)d_in[16];
  const float* ln2b = (const float*)d_in[17];
  float* out = (float*)d_out;
  char* ws = (char*)d_ws;
  char* ob = (char*)d_out;

  // ws: only the bf16 transposed weights (4 MB total)
  bf16* wqT = (bf16*)(ws);
  bf16* wkT = (bf16*)(ws + 524288);
  bf16* wvT = (bf16*)(ws + 1048576);
  bf16* woT = (bf16*)(ws + 1572864);
  bf16* w1T = (bf16*)(ws + 2097152);
  bf16* w2T = (bf16*)(ws + 3145728);

  // d_out-hosted scratch regions
  char* R0 = ob;               // 16,777,216 B
  char* R1 = ob + 16809984;    // 16,777,216 B
  char* R2 = ob + 33587200;    // 16,777,216 B
  bf16*  qb      = (bf16*)R0;
  bf16*  ctx     = (bf16*)R0;
  bf16*  x1b     = (bf16*)R0;
  float* ybuf    = (float*)R0;
  bf16*  Qb      = (bf16*)R1;
  bf16*  Kb      = (bf16*)(R1 + 8388608);
  float* attnres = (float*)R1;
  bf16*  hbuf    = (bf16*)R1;
  bf16*  Vb      = (bf16*)R2;
  bf16*  VtG     = (bf16*)(R2 + 8388608);
  float* x1f     = (float*)R2;

  const dim3 blk(256);

  // prep: weight transposes (N x K bf16) + query bf16
  wcvt_k<<<dim3(16, 16), blk, 0, stream>>>(wq, wqT, 512, 512);
  wcvt_k<<<dim3(16, 16), blk, 0, stream>>>(wk, wkT, 512, 512);
  wcvt_k<<<dim3(16, 16), blk, 0, stream>>>(wv, wvT, 512, 512);
  wcvt_k<<<dim3(16, 16), blk, 0, stream>>>(wo, woT, 512, 512);
  wcvt_k<<<dim3(32, 16), blk, 0, stream>>>(w1, w1T, 512, 1024);
  wcvt_k<<<dim3(16, 32), blk, 0, stream>>>(w2, w2T, 1024, 512);
  cvt_k<<<2048, blk, 0, stream>>>(query, qb);

  // QKV projections
  gemm_k<0><<<dim3(64, 4), blk, 0, stream>>>(qb, wqT, bq, nullptr, Qb, nullptr, 8192, 512, 512);
  gemm_k<0><<<dim3(64, 4), blk, 0, stream>>>(qb, wkT, bk, nullptr, Kb, nullptr, 8192, 512, 512);
  gemm_k<0><<<dim3(64, 4), blk, 0, stream>>>(qb, wvT, bv, nullptr, Vb, nullptr, 8192, 512, 512);

  // V -> per-bh transposed [64][1024]
  vtr_k<<<dim3(16, 64), blk, 0, stream>>>(Vb, VtG);

  // attention -> ctx (R0; qb dead after QKV)
  attn_k<<<dim3(16, 64), blk, 0, stream>>>(Qb, Kb, VtG, qmask, ctx);

  // out-proj + residual(query) -> attnres f32 (R1; overwrites Q+K)
  gemm_k<1><<<dim3(64, 4), blk, 0, stream>>>(ctx, woT, bo, query, nullptr, attnres, 8192, 512, 512);

  // LN1 -> x1f f32 (R2; V/Vt dead) + x1b bf16 (R0; ctx dead)
  ln_k<1><<<2048, blk, 0, stream>>>(attnres, ln1g, ln1b, x1f, x1b);

  // FFN1: relu(x1 @ w1 + b1) -> h bf16 (R1; attnres dead)
  gemm_k<2><<<dim3(64, 8), blk, 0, stream>>>(x1b, w1T, b1, nullptr, hbuf, nullptr, 8192, 1024, 512);

  // FFN2 + residual(x1f) -> ybuf f32 (R0; x1b dead)
  gemm_k<1><<<dim3(64, 4), blk, 0, stream>>>(hbuf, w2T, b2, x1f, nullptr, ybuf, 8192, 512, 1024);

  // LN2 -> out2 straight into d_out (in-place over ybuf)
  ln_k<0><<<2048, blk, 0, stream>>>(ybuf, ln2g, ln2b, out, nullptr);

  // aux outputs: masks as f32, query passthrough copies (overwrite R1/R2)
  mask_k<<<32, blk, 0, stream>>>(qmask, out);
  hipMemcpyAsync(out + 4202496, query, 16777216, hipMemcpyDeviceToDevice, stream);
  hipMemcpyAsync(out + 8396800, query, 16777216, hipMemcpyDeviceToDevice, stream);
}

// Round 4
// 246.291 us; speedup vs baseline: 1.2509x; 1.2509x over previous
//
#include <hip/hip_runtime.h>
#include <hip/hip_bf16.h>

typedef __hip_bfloat16 bf16;
typedef __attribute__((ext_vector_type(4))) float f32x4;
typedef __attribute__((ext_vector_type(8))) short s16x8;

#define MFMA(a, b, c) __builtin_amdgcn_mfma_f32_16x16x32_bf16((a), (b), (c), 0, 0, 0)

__device__ __forceinline__ void g2l16(const bf16* g, bf16* l) {
  __builtin_amdgcn_global_load_lds((const __attribute__((address_space(1))) void*)g,
                                   (__attribute__((address_space(3))) void*)l,
                                   16, 0, 0);
}
__device__ __forceinline__ bf16 cvt_bf(float f) { return __float2bfloat16(f); }
__device__ __forceinline__ float bf2f(bf16 h) { return __bfloat162float(h); }

// ---------------------------------------------------------------------------
// All 6 weight transposes (f32 [K][N] -> bf16 [N][K]) in ONE launch.
// blocks 0-767: wq/wk/wv -> contiguous wqkvT[1536][512]; 768-1023: wo;
// 1024-1535: w1 (512x1024); 1536-2047: w2 (1024x512).
// ---------------------------------------------------------------------------
__global__ __launch_bounds__(256)
void wcvt_all_k(const float* __restrict__ wq, const float* __restrict__ wk,
                const float* __restrict__ wv, const float* __restrict__ wo,
                const float* __restrict__ w1, const float* __restrict__ w2,
                bf16* __restrict__ wqkvT, bf16* __restrict__ woT,
                bf16* __restrict__ w1T, bf16* __restrict__ w2T)
{
  __shared__ float tl[32][33];
  const int bid = blockIdx.x;
  const float* W; bf16* Wt; int K, N, tile;
  if (bid < 768)        { int s = bid >> 8; W = s==0?wq:(s==1?wk:wv);
                          Wt = wqkvT + s*262144; K = 512; N = 512; tile = bid & 255; }
  else if (bid < 1024)  { W = wo; Wt = woT; K = 512;  N = 512;  tile = bid - 768; }
  else if (bid < 1536)  { W = w1; Wt = w1T; K = 512;  N = 1024; tile = bid - 1024; }
  else                  { W = w2; Wt = w2T; K = 1024; N = 512;  tile = bid - 1536; }
  const int nx = N >> 5;
  const int n0 = (tile % nx) * 32, k0 = (tile / nx) * 32;
  const int tx = threadIdx.x & 31, ty = threadIdx.x >> 5;
#pragma unroll
  for (int i = 0; i < 32; i += 8)
    tl[ty + i][tx] = W[(size_t)(k0 + ty + i) * N + n0 + tx];
  __syncthreads();
#pragma unroll
  for (int i = 0; i < 32; i += 8)
    Wt[(size_t)(n0 + ty + i) * K + k0 + tx] = cvt_bf(tl[tx][ty + i]);
}

// ---------------------------------------------------------------------------
// query f32 -> bf16
// ---------------------------------------------------------------------------
__global__ __launch_bounds__(256)
void cvt_k(const float* __restrict__ in, bf16* __restrict__ o)
{
  const int i = (blockIdx.x * 256 + threadIdx.x) * 8;
  float4 a = *(const float4*)(in + i);
  float4 b = *(const float4*)(in + i + 4);
  union { bf16 h[8]; s16x8 v; } u;
  u.h[0] = cvt_bf(a.x); u.h[1] = cvt_bf(a.y); u.h[2] = cvt_bf(a.z); u.h[3] = cvt_bf(a.w);
  u.h[4] = cvt_bf(b.x); u.h[5] = cvt_bf(b.y); u.h[6] = cvt_bf(b.z); u.h[7] = cvt_bf(b.w);
  *(s16x8*)(o + i) = u.v;
}

// ---------------------------------------------------------------------------
// GEMM: C = A[M][K] @ Bt[rows][K]^T, bf16 out. 128xBN tile, BK=64, 4 waves.
// EPI 0: QKV merged (Bt rows = 1536; out/bias selected by n0>>9, stride 512)
// EPI 1: + bias + f32 resid            (out-proj)
// EPI 2: + bias + relu                 (FFN1)
// EPI 3: + bias + bf16 resid           (FFN2)
// Staging: each g2l16 covers 8 rows; 4 waves x (rows/32) iters covers tile.
// ---------------------------------------------------------------------------
template<int BN, int EPI>
__global__ __launch_bounds__(256, 2)
void gemm_k(const bf16* __restrict__ A, const bf16* __restrict__ Bt,
            const float* __restrict__ b0, const float* __restrict__ b1,
            const float* __restrict__ b2,
            const float* __restrict__ rF, const bf16* __restrict__ rB,
            bf16* __restrict__ C0, bf16* __restrict__ C1, bf16* __restrict__ C2,
            int M, int Nout, int K)
{
  constexpr int NI = BN / 32;          // acc cols per wave
  __shared__ bf16 As[128 * 64];
  __shared__ bf16 Bs[BN * 64];
  const int tid = threadIdx.x;
  const int wave = tid >> 6, lane = tid & 63;
  const int g = lane >> 4, c = lane & 15;
  const int m0 = blockIdx.x * 128, n0 = blockIdx.y * BN;
  const int wm = (wave >> 1) * 64, wn = (wave & 1) * (BN / 2);
  const int srl = lane >> 3;
  const int csub = ((lane & 7) ^ (lane >> 3)) * 8;

  f32x4 acc[4][NI];
#pragma unroll
  for (int i = 0; i < 4; ++i)
#pragma unroll
    for (int j = 0; j < NI; ++j) acc[i][j] = (f32x4)0.f;

  for (int k0 = 0; k0 < K; k0 += 64) {
#pragma unroll
    for (int is = 0; is < 4; ++is) {
      const int tr = wave * 32 + is * 8;
      g2l16(A + (size_t)(m0 + tr + srl) * K + (k0 + csub), As + tr * 64);
    }
#pragma unroll
    for (int is = 0; is < BN / 32; ++is) {   // FIX (round 3 bug): BN/32 iters, not BN/64
      const int tr = wave * (BN / 4) + is * 8;
      g2l16(Bt + (size_t)(n0 + tr + srl) * K + (k0 + csub), Bs + tr * 64);
    }
    __syncthreads();
#pragma unroll
    for (int ks = 0; ks < 2; ++ks) {
      s16x8 af[4], bfr[NI];
#pragma unroll
      for (int i = 0; i < 4; ++i) {
        const int ar = wm + i * 16 + c;
        af[i] = *(const s16x8*)((const char*)As + ar * 128 + ((ks * 4 + g) ^ (ar & 7)) * 16);
      }
#pragma unroll
      for (int i = 0; i < NI; ++i) {
        const int br = wn + i * 16 + c;
        bfr[i] = *(const s16x8*)((const char*)Bs + br * 128 + ((ks * 4 + g) ^ (br & 7)) * 16);
      }
#pragma unroll
      for (int mi = 0; mi < 4; ++mi)
#pragma unroll
        for (int ni = 0; ni < NI; ++ni)
          acc[mi][ni] = MFMA(af[mi], bfr[ni], acc[mi][ni]);
    }
    __syncthreads();
  }

  bf16* Cp; const float* bp; int colbase;
  if constexpr (EPI == 0) {
    const int seg = n0 >> 9;
    Cp = seg == 0 ? C0 : (seg == 1 ? C1 : C2);
    bp = seg == 0 ? b0 : (seg == 1 ? b1 : b2);
    colbase = n0 & 511;
  } else { Cp = C0; bp = b0; colbase = n0; }

#pragma unroll
  for (int ni = 0; ni < NI; ++ni) {
    const int col = colbase + wn + ni * 16 + c;
    const float bv = bp[col];
#pragma unroll
    for (int mi = 0; mi < 4; ++mi) {
#pragma unroll
      for (int r = 0; r < 4; ++r) {
        const int row = m0 + wm + mi * 16 + g * 4 + r;
        float v = acc[mi][ni][r] + bv;
        if constexpr (EPI == 1) v += rF[(size_t)row * Nout + col];
        if constexpr (EPI == 2) v = fmaxf(v, 0.f);
        if constexpr (EPI == 3) v += bf2f(rB[(size_t)row * Nout + col]);
        Cp[(size_t)row * Nout + col] = cvt_bf(v);
      }
    }
  }
}

// ---------------------------------------------------------------------------
// V transpose: V (per-bh [1024 k][64 d]) -> Vt per-bh [64 d][1024 k]
// ---------------------------------------------------------------------------
__global__ __launch_bounds__(256)
void vtr_k(const bf16* __restrict__ V, bf16* __restrict__ Vt)
{
  __shared__ bf16 tl[64][72];
  const int bh = blockIdx.y, kt = blockIdx.x;
  const int r = threadIdx.x >> 2, c = threadIdx.x & 3;
  const bf16* src = V + (size_t)bh * 65536 + (size_t)(kt * 64 + r) * 64 + c * 16;
  *(s16x8*)&tl[r][c * 16]     = *(const s16x8*)(src);
  *(s16x8*)&tl[r][c * 16 + 8] = *(const s16x8*)(src + 8);
  __syncthreads();
  union { bf16 h[8]; s16x8 v; } u0, u1;
#pragma unroll
  for (int j = 0; j < 8; ++j) { u0.h[j] = tl[c * 16 + j][r]; u1.h[j] = tl[c * 16 + 8 + j][r]; }
  bf16* dst = Vt + (size_t)bh * 65536 + (size_t)r * 1024 + kt * 64 + c * 16;
  *(s16x8*)dst = u0.v;
  *(s16x8*)(dst + 8) = u1.v;
}

// ---------------------------------------------------------------------------
// Attention: ctx = (exp(QK^T/8)*mask) @ V / max(rowsum,1)
// KVBLK=64 per iter (16 iters), 4 waves x 16 q-rows, 1D grid with XCD swizzle.
// Ks: [64][64] chunk-swizzled by row&7 (pre-swizzled g2l16 source).
// Vs: [64 d][64 k] chunk-swizzled by d&7  (pre-swizzled g2l16 source).
// Ps: per-wave [16 q][64 k], col ^= (q>>2)<<4  -> conflict-free write AND read.
// ---------------------------------------------------------------------------
__global__ __launch_bounds__(256, 4)
void attn_k(const bf16* __restrict__ Q, const bf16* __restrict__ Kp,
            const bf16* __restrict__ Vt, const int* __restrict__ mask,
            bf16* __restrict__ ctx)
{
  __shared__ bf16 Ks[64 * 64];
  __shared__ bf16 Vs[64 * 64];
  __shared__ bf16 Ps[4][16 * 64];
  const int lane = threadIdx.x & 63, wave = threadIdx.x >> 6;
  const int g = lane >> 4, c = lane & 15;
  // XCD-aware swizzle: 1024 blocks, 8 XCDs -> 8 consecutive bh per XCD L2
  const int wg = blockIdx.x;
  const int swz = (wg & 7) * 128 + (wg >> 3);
  const int qb = swz & 15, bh = swz >> 4;
  const int q0 = qb * 64 + wave * 16;
  const bf16* Qg = Q  + (size_t)bh * 65536;
  const bf16* Kg = Kp + (size_t)bh * 65536;
  const bf16* Vg = Vt + (size_t)bh * 65536;
  const int* mrow = mask + (bh & 7) * 1024;
  bf16* Pw = Ps[wave];

  const s16x8 qa0 = *(const s16x8*)(Qg + (size_t)(q0 + c) * 64 + g * 8);
  const s16x8 qa1 = *(const s16x8*)(Qg + (size_t)(q0 + c) * 64 + 32 + g * 8);
  int mq[4];
#pragma unroll
  for (int r = 0; r < 4; ++r) mq[r] = mrow[q0 + g * 4 + r];

  s16x8 ones;
#pragma unroll
  for (int i = 0; i < 8; ++i) ones[i] = (short)0x3F80;

  f32x4 actx[4];
#pragma unroll
  for (int i = 0; i < 4; ++i) actx[i] = (f32x4)0.f;
  f32x4 asum = (f32x4)0.f;

  const int rl = lane >> 3, ch = lane & 7;
  const int schunk = (ch ^ rl) * 8;   // pre-swizzled source chunk (row&7 == rl)

  for (int kt = 0; kt < 16; ++kt) {
    // stage K (64 krow x 64 dh) and Vt (64 d x 64 k) tiles, swizzled sources
#pragma unroll
    for (int rnd = 0; rnd < 2; ++rnd) {
      const int rb = wave * 16 + rnd * 8;
      g2l16(Kg + (size_t)(kt * 64 + rb + rl) * 64 + schunk, Ks + rb * 64);
      g2l16(Vg + (size_t)(rb + rl) * 1024 + kt * 64 + schunk, Vs + rb * 64);
    }
    __syncthreads();

    // QK^T -> exp -> Ps (swizzled, per-wave; no barrier needed before PV)
#pragma unroll
    for (int kb = 0; kb < 4; ++kb) {
      const int krow = kb * 16 + c;
      const char* kbase = (const char*)Ks + krow * 128;
      s16x8 kf0 = *(const s16x8*)(kbase + ((g    ) ^ (krow & 7)) * 16);
      s16x8 kf1 = *(const s16x8*)(kbase + ((g + 4) ^ (krow & 7)) * 16);
      f32x4 z = (f32x4)0.f;
      z = MFMA(qa0, kf0, z);
      z = MFMA(qa1, kf1, z);
      const int mk = mrow[kt * 64 + krow];
#pragma unroll
      for (int r = 0; r < 4; ++r) {
        const float e = (mk && mq[r]) ? __expf(z[r] * 0.125f) : 0.f;
        Pw[(g * 4 + r) * 64 + ((kb * 16 + c) ^ (g * 16))] = cvt_bf(e);
      }
    }

    // PV + rowsum (lane roles: q = c, k-group = g)
#pragma unroll
    for (int kk = 0; kk < 2; ++kk) {
      const s16x8 pa = *(const s16x8*)((const char*)Pw + c * 128
                         + 2 * ((kk * 32 + 8 * g) ^ ((c >> 2) << 4)));
      asum = MFMA(pa, ones, asum);
#pragma unroll
      for (int db = 0; db < 4; ++db) {
        const s16x8 vf = *(const s16x8*)((const char*)Vs + (db * 16 + c) * 128
                           + 16 * ((4 * kk + g) ^ (c & 7)));
        actx[db] = MFMA(pa, vf, actx[db]);
      }
    }
    __syncthreads();
  }

#pragma unroll
  for (int r = 0; r < 4; ++r) {
    const float inv = 1.f / fmaxf(asum[r], 1.f);
    const int qr = q0 + g * 4 + r;
#pragma unroll
    for (int db = 0; db < 4; ++db)
      ctx[(size_t)bh * 65536 + (size_t)qr * 64 + db * 16 + c] = cvt_bf(actx[db][r] * inv);
  }
}

// ---------------------------------------------------------------------------
// LayerNorm D=512. 1 wave/row. INB: bf16 input; OUTF: f32 out; OUTB: bf16 out.
// ---------------------------------------------------------------------------
template<int INB, int OUTF, int OUTB>
__global__ __launch_bounds__(256)
void ln_k(const void* __restrict__ xin, const float* __restrict__ g,
          const float* __restrict__ bb, float* __restrict__ of, bf16* __restrict__ ob)
{
  const int row = blockIdx.x * 4 + (threadIdx.x >> 6);
  const int lane = threadIdx.x & 63;
  float xv[8];
  if constexpr (INB) {
    union { s16x8 v; bf16 h[8]; } u;
    u.v = *(const s16x8*)((const bf16*)xin + (size_t)row * 512 + lane * 8);
#pragma unroll
    for (int j = 0; j < 8; ++j) xv[j] = bf2f(u.h[j]);
  } else {
    const float* xr = (const float*)xin + (size_t)row * 512 + lane * 8;
    float4 a = *(const float4*)xr, b = *(const float4*)(xr + 4);
    xv[0]=a.x; xv[1]=a.y; xv[2]=a.z; xv[3]=a.w; xv[4]=b.x; xv[5]=b.y; xv[6]=b.z; xv[7]=b.w;
  }
  float s = 0.f, q = 0.f;
#pragma unroll
  for (int j = 0; j < 8; ++j) { s += xv[j]; q += xv[j] * xv[j]; }
#pragma unroll
  for (int m = 1; m < 64; m <<= 1) { s += __shfl_xor(s, m); q += __shfl_xor(q, m); }
  const float mu = s * (1.f / 512.f);
  const float var = q * (1.f / 512.f) - mu * mu;
  const float rs = rsqrtf(var + 1e-5f);
  float4 g0 = *(const float4*)(g + lane * 8),  g1 = *(const float4*)(g + lane * 8 + 4);
  float4 b0 = *(const float4*)(bb + lane * 8), b1 = *(const float4*)(bb + lane * 8 + 4);
  float gv[8] = {g0.x, g0.y, g0.z, g0.w, g1.x, g1.y, g1.z, g1.w};
  float bv[8] = {b0.x, b0.y, b0.z, b0.w, b1.x, b1.y, b1.z, b1.w};
  float ov[8];
#pragma unroll
  for (int j = 0; j < 8; ++j) ov[j] = (xv[j] - mu) * rs * gv[j] + bv[j];
  if constexpr (OUTF) {
    float4 o0 = {ov[0], ov[1], ov[2], ov[3]};
    float4 o1 = {ov[4], ov[5], ov[6], ov[7]};
    float* outr = of + (size_t)row * 512 + lane * 8;
    *(float4*)outr = o0;
    *(float4*)(outr + 4) = o1;
  }
  if constexpr (OUTB) {
    union { bf16 h[8]; s16x8 v; } u;
#pragma unroll
    for (int j = 0; j < 8; ++j) u.h[j] = cvt_bf(ov[j]);
    *(s16x8*)(ob + (size_t)row * 512 + lane * 8) = u.v;
  }
}

// ---------------------------------------------------------------------------
__global__ __launch_bounds__(256)
void mask_k(const int* __restrict__ m, float* __restrict__ out)
{
  const int i = blockIdx.x * 256 + threadIdx.x;
  const float v = (float)m[i];
  out[4194304 + i] = v;
  out[12591104 + i] = v;
}

// ---------------------------------------------------------------------------
// Scratch: ws holds only bf16 weights (4MB). All activations live in d_out:
//   R0 [0,16.78M):        qb -> ctx -> x1b(FFN2 resid) -> out2(f32, last)
//   R1 [16.81M,+16.78M):  Qb+Kb -> attnres(bf16) -> hbuf
//   R2 [33.59M,+16.78M):  Vb+VtG -> ybuf(bf16)
// ---------------------------------------------------------------------------
extern "C" void kernel_launch(void* const* d_in, const int* in_sizes, int n_in,
                              void* d_out, int out_size, void* d_ws, size_t ws_size,
                              hipStream_t stream)
{
  const float* query = (const float*)d_in[0];
  const int*   qmask = (const int*)d_in[1];
  const float* wq = (const float*)d_in[2];
  const float* bq = (const float*)d_in[3];
  const float* wk = (const float*)d_in[4];
  const float* bk = (const float*)d_in[5];
  const float* wv = (const float*)d_in[6];
  const float* bv = (const float*)d_in[7];
  const float* wo = (const float*)d_in[8];
  const float* bo = (const float*)d_in[9];
  const float* ln1g = (const float*)d_in[10];
  const float* ln1b = (const float*)d_in[11];
  const float* w1 = (const float*)d_in[12];
  const float* b1 = (const float*)d_in[13];
  const float* w2 = (const float*)d_in[14];
  const float* b2 = (const float*)d_in[15];
  const float* ln2g = (const float*)d_in[16];
  const float* ln2b = (const float*)d_in[17];
  float* out = (float*)d_out;
  char* ws = (char*)d_ws;
  char* ob = (char*)d_out;

  bf16* wqkvT = (bf16*)(ws);              // [1536][512]
  bf16* woT   = (bf16*)(ws + 1572864);    // [512][512]
  bf16* w1T   = (bf16*)(ws + 2097152);    // [1024][512]
  bf16* w2T   = (bf16*)(ws + 3145728);    // [512][1024]

  char* R0 = ob;
  char* R1 = ob + 16809984;
  char* R2 = ob + 33587200;
  bf16*  qb    = (bf16*)R0;
  bf16*  ctx   = (bf16*)R0;
  bf16*  x1b   = (bf16*)R0;
  bf16*  Qb    = (bf16*)R1;
  bf16*  Kb    = (bf16*)(R1 + 8388608);
  bf16*  attnr = (bf16*)R1;
  bf16*  hbuf  = (bf16*)R1;
  bf16*  Vb    = (bf16*)R2;
  bf16*  VtG   = (bf16*)(R2 + 8388608);
  bf16*  ybuf  = (bf16*)R2;

  const dim3 blk(256);

  wcvt_all_k<<<2048, blk, 0, stream>>>(wq, wk, wv, wo, w1, w2, wqkvT, woT, w1T, w2T);
  cvt_k<<<2048, blk, 0, stream>>>(query, qb);

  // QKV merged: A=qb, Bt=wqkvT[1536][512]; outputs selected per n-block
  gemm_k<128, 0><<<dim3(64, 12), blk, 0, stream>>>(qb, wqkvT, bq, bk, bv,
      nullptr, nullptr, Qb, Kb, Vb, 8192, 512, 512);

  vtr_k<<<dim3(16, 64), blk, 0, stream>>>(Vb, VtG);

  attn_k<<<1024, blk, 0, stream>>>(Qb, Kb, VtG, qmask, ctx);

  // out-proj + f32 resid(query) -> attnr bf16
  gemm_k<64, 1><<<dim3(64, 8), blk, 0, stream>>>(ctx, woT, bo, nullptr, nullptr,
      query, nullptr, attnr, nullptr, nullptr, 8192, 512, 512);

  // LN1: bf16 in -> bf16 x1b
  ln_k<1, 0, 1><<<2048, blk, 0, stream>>>(attnr, ln1g, ln1b, nullptr, x1b);

  // FFN1: relu(x1 @ w1 + b1) -> hbuf bf16
  gemm_k<128, 2><<<dim3(64, 8), blk, 0, stream>>>(x1b, w1T, b1, nullptr, nullptr,
      nullptr, nullptr, hbuf, nullptr, nullptr, 8192, 1024, 512);

  // FFN2 + bf16 resid(x1b) -> ybuf bf16
  gemm_k<64, 3><<<dim3(64, 8), blk, 0, stream>>>(hbuf, w2T, b2, nullptr, nullptr,
      nullptr, x1b, ybuf, nullptr, nullptr, 8192, 512, 1024);

  // LN2: bf16 in -> f32 out2 (R2 -> R0, no overlap)
  ln_k<1, 1, 0><<<2048, blk, 0, stream>>>(ybuf, ln2g, ln2b, out, nullptr);

  mask_k<<<32, blk, 0, stream>>>(qmask, out);
  hipMemcpyAsync(out + 4202496, query, 16777216, hipMemcpyDeviceToDevice, stream);
  hipMemcpyAsync(out + 8396800, query, 16777216, hipMemcpyDeviceToDevice, stream);
}

// Round 5
// 225.610 us; speedup vs baseline: 1.3655x; 1.0917x over previous
//
#include <hip/hip_runtime.h>
#include <hip/hip_bf16.h>

typedef __hip_bfloat16 bf16;
typedef __attribute__((ext_vector_type(4))) float f32x4;
typedef __attribute__((ext_vector_type(8))) short s16x8;

#define MFMA(a, b, c) __builtin_amdgcn_mfma_f32_16x16x32_bf16((a), (b), (c), 0, 0, 0)

__device__ __forceinline__ void g2l16(const bf16* g, bf16* l) {
  __builtin_amdgcn_global_load_lds((const __attribute__((address_space(1))) void*)g,
                                   (__attribute__((address_space(3))) void*)l,
                                   16, 0, 0);
}
__device__ __forceinline__ bf16 cvt_bf(float f) { return __float2bfloat16(f); }
__device__ __forceinline__ float bf2f(bf16 h) { return __bfloat162float(h); }

// ---------------------------------------------------------------------------
// All 6 weight transposes (f32 [K][N] -> bf16 [N][K]) in ONE launch.
// ---------------------------------------------------------------------------
__global__ __launch_bounds__(256)
void wcvt_all_k(const float* __restrict__ wq, const float* __restrict__ wk,
                const float* __restrict__ wv, const float* __restrict__ wo,
                const float* __restrict__ w1, const float* __restrict__ w2,
                bf16* __restrict__ wqkvT, bf16* __restrict__ woT,
                bf16* __restrict__ w1T, bf16* __restrict__ w2T)
{
  __shared__ float tl[32][33];
  const int bid = blockIdx.x;
  const float* W; bf16* Wt; int K, N, tile;
  if (bid < 768)        { int s = bid >> 8; W = s==0?wq:(s==1?wk:wv);
                          Wt = wqkvT + s*262144; K = 512; N = 512; tile = bid & 255; }
  else if (bid < 1024)  { W = wo; Wt = woT; K = 512;  N = 512;  tile = bid - 768; }
  else if (bid < 1536)  { W = w1; Wt = w1T; K = 512;  N = 1024; tile = bid - 1024; }
  else                  { W = w2; Wt = w2T; K = 1024; N = 512;  tile = bid - 1536; }
  const int nx = N >> 5;
  const int n0 = (tile % nx) * 32, k0 = (tile / nx) * 32;
  const int tx = threadIdx.x & 31, ty = threadIdx.x >> 5;
#pragma unroll
  for (int i = 0; i < 32; i += 8)
    tl[ty + i][tx] = W[(size_t)(k0 + ty + i) * N + n0 + tx];
  __syncthreads();
#pragma unroll
  for (int i = 0; i < 32; i += 8)
    Wt[(size_t)(n0 + ty + i) * K + k0 + tx] = cvt_bf(tl[tx][ty + i]);
}

// ---------------------------------------------------------------------------
// query f32 -> bf16
// ---------------------------------------------------------------------------
__global__ __launch_bounds__(256)
void cvt_k(const float* __restrict__ in, bf16* __restrict__ o)
{
  const int i = (blockIdx.x * 256 + threadIdx.x) * 8;
  float4 a = *(const float4*)(in + i);
  float4 b = *(const float4*)(in + i + 4);
  union { bf16 h[8]; s16x8 v; } u;
  u.h[0] = cvt_bf(a.x); u.h[1] = cvt_bf(a.y); u.h[2] = cvt_bf(a.z); u.h[3] = cvt_bf(a.w);
  u.h[4] = cvt_bf(b.x); u.h[5] = cvt_bf(b.y); u.h[6] = cvt_bf(b.z); u.h[7] = cvt_bf(b.w);
  *(s16x8*)(o + i) = u.v;
}

// ---------------------------------------------------------------------------
// GEMM: C = A[M][K] @ Bt[rows][K]^T, bf16 out. 128xBN tile, BK=64, 4 waves.
// EPI 0: QKV merged; EPI 1: +bias+f32 resid; EPI 2: +bias+relu; EPI 3: +bias+bf16 resid
// ---------------------------------------------------------------------------
template<int BN, int EPI>
__global__ __launch_bounds__(256, 2)
void gemm_k(const bf16* __restrict__ A, const bf16* __restrict__ Bt,
            const float* __restrict__ b0, const float* __restrict__ b1,
            const float* __restrict__ b2,
            const float* __restrict__ rF, const bf16* __restrict__ rB,
            bf16* __restrict__ C0, bf16* __restrict__ C1, bf16* __restrict__ C2,
            int M, int Nout, int K)
{
  constexpr int NI = BN / 32;
  __shared__ bf16 As[128 * 64];
  __shared__ bf16 Bs[BN * 64];
  const int tid = threadIdx.x;
  const int wave = tid >> 6, lane = tid & 63;
  const int g = lane >> 4, c = lane & 15;
  const int m0 = blockIdx.x * 128, n0 = blockIdx.y * BN;
  const int wm = (wave >> 1) * 64, wn = (wave & 1) * (BN / 2);
  const int srl = lane >> 3;
  const int csub = ((lane & 7) ^ (lane >> 3)) * 8;

  f32x4 acc[4][NI];
#pragma unroll
  for (int i = 0; i < 4; ++i)
#pragma unroll
    for (int j = 0; j < NI; ++j) acc[i][j] = (f32x4)0.f;

  for (int k0 = 0; k0 < K; k0 += 64) {
#pragma unroll
    for (int is = 0; is < 4; ++is) {
      const int tr = wave * 32 + is * 8;
      g2l16(A + (size_t)(m0 + tr + srl) * K + (k0 + csub), As + tr * 64);
    }
#pragma unroll
    for (int is = 0; is < BN / 32; ++is) {
      const int tr = wave * (BN / 4) + is * 8;
      g2l16(Bt + (size_t)(n0 + tr + srl) * K + (k0 + csub), Bs + tr * 64);
    }
    __syncthreads();
#pragma unroll
    for (int ks = 0; ks < 2; ++ks) {
      s16x8 af[4], bfr[NI];
#pragma unroll
      for (int i = 0; i < 4; ++i) {
        const int ar = wm + i * 16 + c;
        af[i] = *(const s16x8*)((const char*)As + ar * 128 + ((ks * 4 + g) ^ (ar & 7)) * 16);
      }
#pragma unroll
      for (int i = 0; i < NI; ++i) {
        const int br = wn + i * 16 + c;
        bfr[i] = *(const s16x8*)((const char*)Bs + br * 128 + ((ks * 4 + g) ^ (br & 7)) * 16);
      }
#pragma unroll
      for (int mi = 0; mi < 4; ++mi)
#pragma unroll
        for (int ni = 0; ni < NI; ++ni)
          acc[mi][ni] = MFMA(af[mi], bfr[ni], acc[mi][ni]);
    }
    __syncthreads();
  }

  bf16* Cp; const float* bp; int colbase;
  if constexpr (EPI == 0) {
    const int seg = n0 >> 9;
    Cp = seg == 0 ? C0 : (seg == 1 ? C1 : C2);
    bp = seg == 0 ? b0 : (seg == 1 ? b1 : b2);
    colbase = n0 & 511;
  } else { Cp = C0; bp = b0; colbase = n0; }

#pragma unroll
  for (int ni = 0; ni < NI; ++ni) {
    const int col = colbase + wn + ni * 16 + c;
    const float bv = bp[col];
#pragma unroll
    for (int mi = 0; mi < 4; ++mi) {
#pragma unroll
      for (int r = 0; r < 4; ++r) {
        const int row = m0 + wm + mi * 16 + g * 4 + r;
        float v = acc[mi][ni][r] + bv;
        if constexpr (EPI == 1) v += rF[(size_t)row * Nout + col];
        if constexpr (EPI == 2) v = fmaxf(v, 0.f);
        if constexpr (EPI == 3) v += bf2f(rB[(size_t)row * Nout + col]);
        Cp[(size_t)row * Nout + col] = cvt_bf(v);
      }
    }
  }
}

// ---------------------------------------------------------------------------
// V transpose: V (per-bh [1024 k][64 d]) -> Vt per-bh [64 d][1024 k]
// ---------------------------------------------------------------------------
__global__ __launch_bounds__(256)
void vtr_k(const bf16* __restrict__ V, bf16* __restrict__ Vt)
{
  __shared__ bf16 tl[64][72];
  const int bh = blockIdx.y, kt = blockIdx.x;
  const int r = threadIdx.x >> 2, c = threadIdx.x & 3;
  const bf16* src = V + (size_t)bh * 65536 + (size_t)(kt * 64 + r) * 64 + c * 16;
  *(s16x8*)&tl[r][c * 16]     = *(const s16x8*)(src);
  *(s16x8*)&tl[r][c * 16 + 8] = *(const s16x8*)(src + 8);
  __syncthreads();
  union { bf16 h[8]; s16x8 v; } u0, u1;
#pragma unroll
  for (int j = 0; j < 8; ++j) { u0.h[j] = tl[c * 16 + j][r]; u1.h[j] = tl[c * 16 + 8 + j][r]; }
  bf16* dst = Vt + (size_t)bh * 65536 + (size_t)r * 1024 + kt * 64 + c * 16;
  *(s16x8*)dst = u0.v;
  *(s16x8*)(dst + 8) = u1.v;
}

// ---------------------------------------------------------------------------
// Attention v2: LDS-traffic-minimized. ctx = (exp(QK^T/8 + koff)) @ V * qm / max(sum,1)
// 4 waves x 32 q-rows (128 q/block), KVBLK=64, double-buffered K/V staging.
// Swapped QK^T (z = K.Q^T) + sigma-permuted K staging => exp'd P stays in
// REGISTERS and feeds PV MFMA A-operand directly (no P LDS round-trip).
// k-mask staged once as additive offsets koff[1024] (0 / -1e30).
// ---------------------------------------------------------------------------
__global__ __launch_bounds__(256, 2)
void attn_k(const bf16* __restrict__ Q, const bf16* __restrict__ Kp,
            const bf16* __restrict__ Vt, const int* __restrict__ mask,
            bf16* __restrict__ ctx)
{
  __shared__ bf16 Ks[2][64 * 64];
  __shared__ bf16 Vs[2][64 * 64];
  __shared__ __align__(16) float koff[1024];
  const int lane = threadIdx.x & 63, wave = threadIdx.x >> 6;
  const int g = lane >> 4, c = lane & 15;
  const int wg = blockIdx.x;                   // 512 blocks
  const int swz = (wg & 7) * 64 + (wg >> 3);   // 8 consecutive bh per XCD
  const int qb = swz & 7, bh = swz >> 3;
  const int q0w = qb * 128 + wave * 32;
  const bf16* Qg = Q  + (size_t)bh * 65536;
  const bf16* Kg = Kp + (size_t)bh * 65536;
  const bf16* Vg = Vt + (size_t)bh * 65536;
  const int* mrow = mask + (bh & 7) * 1024;

  // stage k-mask as additive offsets (once)
  {
    const int i = threadIdx.x * 4;
    int4 m4 = *(const int4*)(mrow + i);
    f32x4 kv;
    kv[0] = m4.x ? 0.f : -1e30f;
    kv[1] = m4.y ? 0.f : -1e30f;
    kv[2] = m4.z ? 0.f : -1e30f;
    kv[3] = m4.w ? 0.f : -1e30f;
    *(f32x4*)&koff[i] = kv;
  }

  // Q fragments (B-operand of swapped QK^T): 2 q-subtiles x 2 dh-halves
  s16x8 qa[2][2];
#pragma unroll
  for (int qs = 0; qs < 2; ++qs)
#pragma unroll
    for (int h = 0; h < 2; ++h)
      qa[qs][h] = *(const s16x8*)(Qg + (size_t)(q0w + qs * 16 + c) * 64 + h * 32 + g * 8);

  // q-mask multipliers for this lane's output rows (q = q0w + qs*16 + g*4 + r)
  float qm[2][4];
#pragma unroll
  for (int qs = 0; qs < 2; ++qs)
#pragma unroll
    for (int r = 0; r < 4; ++r)
      qm[qs][r] = mrow[q0w + qs * 16 + g * 4 + r] ? 1.f : 0.f;

  s16x8 ones;
#pragma unroll
  for (int i = 0; i < 8; ++i) ones[i] = (short)0x3F80;

  f32x4 acc[2][4], asum[2];
#pragma unroll
  for (int qs = 0; qs < 2; ++qs) {
    asum[qs] = (f32x4)0.f;
#pragma unroll
    for (int db = 0; db < 4; ++db) acc[qs][db] = (f32x4)0.f;
  }

  const int rl = lane >> 3, ch = lane & 7;
  const int schunk = (ch ^ rl) * 8;   // chunk-swizzled source (dest-row&7 = rl)

  // K staged with row-permutation sigma: LDS row l holds K row
  //   sigma(l) = 32*(kb>>1) + 8*(i>>2) + 4*(kb&1) + (i&3),  kb=l>>4, i=l&15
  // so register P fragments match the PV A-operand k-mapping.
  auto STAGE = [&](int kt, int buf) {
#pragma unroll
    for (int rnd = 0; rnd < 2; ++rnd) {
      const int rb = wave * 16 + rnd * 8;
      const int l = rb + rl;
      const int i16 = l & 15, kbb = l >> 4;
      const int srow = ((kbb >> 1) << 5) + ((i16 >> 2) << 3) + ((kbb & 1) << 2) + (i16 & 3);
      g2l16(Kg + (size_t)(kt * 64 + srow) * 64 + schunk, &Ks[buf][rb * 64]);
      g2l16(Vg + (size_t)l * 1024 + kt * 64 + schunk, &Vs[buf][rb * 64]);
    }
  };

  STAGE(0, 0);
  __syncthreads();

  for (int kt = 0; kt < 16; ++kt) {
    const int cur = kt & 1;
    if (kt < 15) STAGE(kt + 1, cur ^ 1);

    union { unsigned w[8]; s16x8 v[2]; } pr[2];

    // QK^T (swapped) + exp: z[r] = S[k = sigma-mapped][q=c]
#pragma unroll
    for (int kb = 0; kb < 4; ++kb) {
      const int krow = kb * 16 + c;
      const char* kbase = (const char*)&Ks[cur][0] + krow * 128;
      const s16x8 kf0 = *(const s16x8*)(kbase + ((g    ) ^ (c & 7)) * 16);
      const s16x8 kf1 = *(const s16x8*)(kbase + ((g + 4) ^ (c & 7)) * 16);
      // global k for (kb,g,r) = kt*64 + 32*(kb>>1) + 8*g + 4*(kb&1) + r
      const f32x4 ko = *(const f32x4*)&koff[kt * 64 + ((kb >> 1) << 5) + (g << 3) + ((kb & 1) << 2)];
#pragma unroll
      for (int qs = 0; qs < 2; ++qs) {
        f32x4 z = (f32x4)0.f;
        z = MFMA(kf0, qa[qs][0], z);
        z = MFMA(kf1, qa[qs][1], z);
        union { bf16 h[4]; unsigned u[2]; } eh;
#pragma unroll
        for (int r = 0; r < 4; ++r)
          eh.h[r] = cvt_bf(__expf(fmaf(z[r], 0.125f, ko[r])));
        pr[qs].w[kb * 2]     = eh.u[0];
        pr[qs].w[kb * 2 + 1] = eh.u[1];
      }
    }

    // PV + rowsum; P fragments straight from registers
#pragma unroll
    for (int kk = 0; kk < 2; ++kk) {
      s16x8 vf[4];
#pragma unroll
      for (int db = 0; db < 4; ++db)
        vf[db] = *(const s16x8*)((const char*)&Vs[cur][0] + (db * 16 + c) * 128 + ((4 * kk + g) ^ (c & 7)) * 16);
#pragma unroll
      for (int qs = 0; qs < 2; ++qs) {
        const s16x8 pa = pr[qs].v[kk];
        asum[qs] = MFMA(pa, ones, asum[qs]);
#pragma unroll
        for (int db = 0; db < 4; ++db)
          acc[qs][db] = MFMA(pa, vf[db], acc[qs][db]);
      }
    }
    __syncthreads();
  }

#pragma unroll
  for (int qs = 0; qs < 2; ++qs)
#pragma unroll
    for (int r = 0; r < 4; ++r) {
      const float inv = qm[qs][r] / fmaxf(asum[qs][r], 1.f);
      const size_t qr = q0w + qs * 16 + g * 4 + r;
#pragma unroll
      for (int db = 0; db < 4; ++db)
        ctx[(size_t)bh * 65536 + qr * 64 + db * 16 + c] = cvt_bf(acc[qs][db][r] * inv);
    }
}

// ---------------------------------------------------------------------------
// LayerNorm D=512. 1 wave/row. INB: bf16 input; OUTF: f32 out; OUTB: bf16 out.
// ---------------------------------------------------------------------------
template<int INB, int OUTF, int OUTB>
__global__ __launch_bounds__(256)
void ln_k(const void* __restrict__ xin, const float* __restrict__ g,
          const float* __restrict__ bb, float* __restrict__ of, bf16* __restrict__ ob)
{
  const int row = blockIdx.x * 4 + (threadIdx.x >> 6);
  const int lane = threadIdx.x & 63;
  float xv[8];
  if constexpr (INB) {
    union { s16x8 v; bf16 h[8]; } u;
    u.v = *(const s16x8*)((const bf16*)xin + (size_t)row * 512 + lane * 8);
#pragma unroll
    for (int j = 0; j < 8; ++j) xv[j] = bf2f(u.h[j]);
  } else {
    const float* xr = (const float*)xin + (size_t)row * 512 + lane * 8;
    float4 a = *(const float4*)xr, b = *(const float4*)(xr + 4);
    xv[0]=a.x; xv[1]=a.y; xv[2]=a.z; xv[3]=a.w; xv[4]=b.x; xv[5]=b.y; xv[6]=b.z; xv[7]=b.w;
  }
  float s = 0.f, q = 0.f;
#pragma unroll
  for (int j = 0; j < 8; ++j) { s += xv[j]; q += xv[j] * xv[j]; }
#pragma unroll
  for (int m = 1; m < 64; m <<= 1) { s += __shfl_xor(s, m); q += __shfl_xor(q, m); }
  const float mu = s * (1.f / 512.f);
  const float var = q * (1.f / 512.f) - mu * mu;
  const float rs = rsqrtf(var + 1e-5f);
  float4 g0 = *(const float4*)(g + lane * 8),  g1 = *(const float4*)(g + lane * 8 + 4);
  float4 b0 = *(const float4*)(bb + lane * 8), b1 = *(const float4*)(bb + lane * 8 + 4);
  float gv[8] = {g0.x, g0.y, g0.z, g0.w, g1.x, g1.y, g1.z, g1.w};
  float bv[8] = {b0.x, b0.y, b0.z, b0.w, b1.x, b1.y, b1.z, b1.w};
  float ov[8];
#pragma unroll
  for (int j = 0; j < 8; ++j) ov[j] = (xv[j] - mu) * rs * gv[j] + bv[j];
  if constexpr (OUTF) {
    float4 o0 = {ov[0], ov[1], ov[2], ov[3]};
    float4 o1 = {ov[4], ov[5], ov[6], ov[7]};
    float* outr = of + (size_t)row * 512 + lane * 8;
    *(float4*)outr = o0;
    *(float4*)(outr + 4) = o1;
  }
  if constexpr (OUTB) {
    union { bf16 h[8]; s16x8 v; } u;
#pragma unroll
    for (int j = 0; j < 8; ++j) u.h[j] = cvt_bf(ov[j]);
    *(s16x8*)(ob + (size_t)row * 512 + lane * 8) = u.v;
  }
}

// ---------------------------------------------------------------------------
__global__ __launch_bounds__(256)
void mask_k(const int* __restrict__ m, float* __restrict__ out)
{
  const int i = blockIdx.x * 256 + threadIdx.x;
  const float v = (float)m[i];
  out[4194304 + i] = v;
  out[12591104 + i] = v;
}

// ---------------------------------------------------------------------------
// Scratch: ws holds bf16 weights (4MB). Activations live in d_out regions:
//   R0 [0,16.78M):        qb -> ctx -> x1b(FFN2 resid) -> out2(f32, last)
//   R1 [16.81M,+16.78M):  Qb+Kb -> attnres(bf16) -> hbuf
//   R2 [33.59M,+16.78M):  Vb+VtG -> ybuf(bf16)
// ---------------------------------------------------------------------------
extern "C" void kernel_launch(void* const* d_in, const int* in_sizes, int n_in,
                              void* d_out, int out_size, void* d_ws, size_t ws_size,
                              hipStream_t stream)
{
  const float* query = (const float*)d_in[0];
  const int*   qmask = (const int*)d_in[1];
  const float* wq = (const float*)d_in[2];
  const float* bq = (const float*)d_in[3];
  const float* wk = (const float*)d_in[4];
  const float* bk = (const float*)d_in[5];
  const float* wv = (const float*)d_in[6];
  const float* bv = (const float*)d_in[7];
  const float* wo = (const float*)d_in[8];
  const float* bo = (const float*)d_in[9];
  const float* ln1g = (const float*)d_in[10];
  const float* ln1b = (const float*)d_in[11];
  const float* w1 = (const float*)d_in[12];
  const float* b1 = (const float*)d_in[13];
  const float* w2 = (const float*)d_in[14];
  const float* b2 = (const float*)d_in[15];
  const float* ln2g = (const float*)d_in[16];
  const float* ln2b = (const float*)d_in[17];
  float* out = (float*)d_out;
  char* ws = (char*)d_ws;
  char* ob = (char*)d_out;

  bf16* wqkvT = (bf16*)(ws);              // [1536][512]
  bf16* woT   = (bf16*)(ws + 1572864);    // [512][512]
  bf16* w1T   = (bf16*)(ws + 2097152);    // [1024][512]
  bf16* w2T   = (bf16*)(ws + 3145728);    // [512][1024]

  char* R0 = ob;
  char* R1 = ob + 16809984;
  char* R2 = ob + 33587200;
  bf16*  qb    = (bf16*)R0;
  bf16*  ctx   = (bf16*)R0;
  bf16*  x1b   = (bf16*)R0;
  bf16*  Qb    = (bf16*)R1;
  bf16*  Kb    = (bf16*)(R1 + 8388608);
  bf16*  attnr = (bf16*)R1;
  bf16*  hbuf  = (bf16*)R1;
  bf16*  Vb    = (bf16*)R2;
  bf16*  VtG   = (bf16*)(R2 + 8388608);
  bf16*  ybuf  = (bf16*)R2;

  const dim3 blk(256);

  wcvt_all_k<<<2048, blk, 0, stream>>>(wq, wk, wv, wo, w1, w2, wqkvT, woT, w1T, w2T);
  cvt_k<<<2048, blk, 0, stream>>>(query, qb);

  // QKV merged: A=qb, Bt=wqkvT[1536][512]; outputs selected per n-block
  gemm_k<128, 0><<<dim3(64, 12), blk, 0, stream>>>(qb, wqkvT, bq, bk, bv,
      nullptr, nullptr, Qb, Kb, Vb, 8192, 512, 512);

  vtr_k<<<dim3(16, 64), blk, 0, stream>>>(Vb, VtG);

  attn_k<<<512, blk, 0, stream>>>(Qb, Kb, VtG, qmask, ctx);

  // out-proj + f32 resid(query) -> attnr bf16
  gemm_k<64, 1><<<dim3(64, 8), blk, 0, stream>>>(ctx, woT, bo, nullptr, nullptr,
      query, nullptr, attnr, nullptr, nullptr, 8192, 512, 512);

  // LN1: bf16 in -> bf16 x1b
  ln_k<1, 0, 1><<<2048, blk, 0, stream>>>(attnr, ln1g, ln1b, nullptr, x1b);

  // FFN1: relu(x1 @ w1 + b1) -> hbuf bf16
  gemm_k<128, 2><<<dim3(64, 8), blk, 0, stream>>>(x1b, w1T, b1, nullptr, nullptr,
      nullptr, nullptr, hbuf, nullptr, nullptr, 8192, 1024, 512);

  // FFN2 + bf16 resid(x1b) -> ybuf bf16
  gemm_k<64, 3><<<dim3(64, 8), blk, 0, stream>>>(hbuf, w2T, b2, nullptr, nullptr,
      nullptr, x1b, ybuf, nullptr, nullptr, 8192, 512, 1024);

  // LN2: bf16 in -> f32 out2 (R2 -> R0, no overlap)
  ln_k<1, 1, 0><<<2048, blk, 0, stream>>>(ybuf, ln2g, ln2b, out, nullptr);

  mask_k<<<32, blk, 0, stream>>>(qmask, out);
  hipMemcpyAsync(out + 4202496, query, 16777216, hipMemcpyDeviceToDevice, stream);
  hipMemcpyAsync(out + 8396800, query, 16777216, hipMemcpyDeviceToDevice, stream);
}

// Round 6
// 219.391 us; speedup vs baseline: 1.4042x; 1.0283x over previous
//
#include <hip/hip_runtime.h>
#include <hip/hip_bf16.h>

typedef __hip_bfloat16 bf16;
typedef __attribute__((ext_vector_type(4))) float f32x4;
typedef __attribute__((ext_vector_type(8))) short s16x8;

#define MFMA(a, b, c) __builtin_amdgcn_mfma_f32_16x16x32_bf16((a), (b), (c), 0, 0, 0)

__device__ __forceinline__ void g2l16(const bf16* g, bf16* l) {
  __builtin_amdgcn_global_load_lds((const __attribute__((address_space(1))) void*)g,
                                   (__attribute__((address_space(3))) void*)l,
                                   16, 0, 0);
}
__device__ __forceinline__ bf16 cvt_bf(float f) { return __float2bfloat16(f); }
__device__ __forceinline__ float bf2f(bf16 h) { return __bfloat162float(h); }

// ---------------------------------------------------------------------------
// All 6 weight transposes (f32 [K][N] -> bf16 [N][K]) in ONE launch.
// ---------------------------------------------------------------------------
__global__ __launch_bounds__(256)
void wcvt_all_k(const float* __restrict__ wq, const float* __restrict__ wk,
                const float* __restrict__ wv, const float* __restrict__ wo,
                const float* __restrict__ w1, const float* __restrict__ w2,
                bf16* __restrict__ wqkvT, bf16* __restrict__ woT,
                bf16* __restrict__ w1T, bf16* __restrict__ w2T)
{
  __shared__ float tl[32][33];
  const int bid = blockIdx.x;
  const float* W; bf16* Wt; int K, N, tile;
  if (bid < 768)        { int s = bid >> 8; W = s==0?wq:(s==1?wk:wv);
                          Wt = wqkvT + s*262144; K = 512; N = 512; tile = bid & 255; }
  else if (bid < 1024)  { W = wo; Wt = woT; K = 512;  N = 512;  tile = bid - 768; }
  else if (bid < 1536)  { W = w1; Wt = w1T; K = 512;  N = 1024; tile = bid - 1024; }
  else                  { W = w2; Wt = w2T; K = 1024; N = 512;  tile = bid - 1536; }
  const int nx = N >> 5;
  const int n0 = (tile % nx) * 32, k0 = (tile / nx) * 32;
  const int tx = threadIdx.x & 31, ty = threadIdx.x >> 5;
#pragma unroll
  for (int i = 0; i < 32; i += 8)
    tl[ty + i][tx] = W[(size_t)(k0 + ty + i) * N + n0 + tx];
  __syncthreads();
#pragma unroll
  for (int i = 0; i < 32; i += 8)
    Wt[(size_t)(n0 + ty + i) * K + k0 + tx] = cvt_bf(tl[tx][ty + i]);
}

// ---------------------------------------------------------------------------
// Fused prep (big-ws path): query f32->bf16 + BOTH query passthrough copies
// + mask f32 writes. Reads query once.
// ---------------------------------------------------------------------------
__global__ __launch_bounds__(256)
void prep_k(const float* __restrict__ query, const int* __restrict__ qmask,
            bf16* __restrict__ qb, float* __restrict__ out)
{
  const int bid = blockIdx.x;
  if (bid < 2048) {
    const int i = bid * 2048 + threadIdx.x * 8;
    float4 a = *(const float4*)(query + i);
    float4 b = *(const float4*)(query + i + 4);
    union { bf16 h[8]; s16x8 v; } u;
    u.h[0] = cvt_bf(a.x); u.h[1] = cvt_bf(a.y); u.h[2] = cvt_bf(a.z); u.h[3] = cvt_bf(a.w);
    u.h[4] = cvt_bf(b.x); u.h[5] = cvt_bf(b.y); u.h[6] = cvt_bf(b.z); u.h[7] = cvt_bf(b.w);
    *(s16x8*)(qb + i) = u.v;
    float* o1 = out + 4202496 + i;
    float* o2 = out + 8396800 + i;
    *(float4*)o1 = a; *(float4*)(o1 + 4) = b;
    *(float4*)o2 = a; *(float4*)(o2 + 4) = b;
  } else {
    const int j = (bid - 2048) * 256 + threadIdx.x;  // 8192 total
    const float v = (float)qmask[j];
    out[4194304 + j] = v;
    out[12591104 + j] = v;
  }
}

// ---------------------------------------------------------------------------
// query f32 -> bf16 (fallback path)
// ---------------------------------------------------------------------------
__global__ __launch_bounds__(256)
void cvt_k(const float* __restrict__ in, bf16* __restrict__ o)
{
  const int i = (blockIdx.x * 256 + threadIdx.x) * 8;
  float4 a = *(const float4*)(in + i);
  float4 b = *(const float4*)(in + i + 4);
  union { bf16 h[8]; s16x8 v; } u;
  u.h[0] = cvt_bf(a.x); u.h[1] = cvt_bf(a.y); u.h[2] = cvt_bf(a.z); u.h[3] = cvt_bf(a.w);
  u.h[4] = cvt_bf(b.x); u.h[5] = cvt_bf(b.y); u.h[6] = cvt_bf(b.z); u.h[7] = cvt_bf(b.w);
  *(s16x8*)(o + i) = u.v;
}

// ---------------------------------------------------------------------------
// GEMM: C = A[8192][K] @ Bt[rows][K]^T, bf16 out. 128xBN tile, BK=64, 4 waves.
// 1D grid, XCD-chunked decode: each XCD owns an 8-wide bx chunk x all by ->
// per-XCD L2 working set = 1MB A slice + B panel (fits 4MB).
// EPI 0: QKV merged; EPI 1: +bias+f32 resid; EPI 2: +bias+relu; EPI 3: +bias+bf16 resid
// ---------------------------------------------------------------------------
template<int BN, int EPI>
__global__ __launch_bounds__(256, 2)
void gemm_k(const bf16* __restrict__ A, const bf16* __restrict__ Bt,
            const float* __restrict__ b0, const float* __restrict__ b1,
            const float* __restrict__ b2,
            const float* __restrict__ rF, const bf16* __restrict__ rB,
            bf16* __restrict__ C0, bf16* __restrict__ C1, bf16* __restrict__ C2,
            int Nout, int K)
{
  constexpr int NI = BN / 32;
  __shared__ bf16 As[128 * 64];
  __shared__ bf16 Bs[BN * 64];
  const int tid = threadIdx.x;
  const int wave = tid >> 6, lane = tid & 63;
  const int g = lane >> 4, c = lane & 15;
  const int wgid = blockIdx.x;
  const int xcd = wgid & 7, idx = wgid >> 3;
  const int m0 = (xcd * 8 + (idx & 7)) * 128;
  const int n0 = (idx >> 3) * BN;
  const int wm = (wave >> 1) * 64, wn = (wave & 1) * (BN / 2);
  const int srl = lane >> 3;
  const int csub = ((lane & 7) ^ (lane >> 3)) * 8;

  f32x4 acc[4][NI];
#pragma unroll
  for (int i = 0; i < 4; ++i)
#pragma unroll
    for (int j = 0; j < NI; ++j) acc[i][j] = (f32x4)0.f;

  for (int k0 = 0; k0 < K; k0 += 64) {
#pragma unroll
    for (int is = 0; is < 4; ++is) {
      const int tr = wave * 32 + is * 8;
      g2l16(A + (size_t)(m0 + tr + srl) * K + (k0 + csub), As + tr * 64);
    }
#pragma unroll
    for (int is = 0; is < BN / 32; ++is) {
      const int tr = wave * (BN / 4) + is * 8;
      g2l16(Bt + (size_t)(n0 + tr + srl) * K + (k0 + csub), Bs + tr * 64);
    }
    __syncthreads();
#pragma unroll
    for (int ks = 0; ks < 2; ++ks) {
      s16x8 af[4], bfr[NI];
#pragma unroll
      for (int i = 0; i < 4; ++i) {
        const int ar = wm + i * 16 + c;
        af[i] = *(const s16x8*)((const char*)As + ar * 128 + ((ks * 4 + g) ^ (ar & 7)) * 16);
      }
#pragma unroll
      for (int i = 0; i < NI; ++i) {
        const int br = wn + i * 16 + c;
        bfr[i] = *(const s16x8*)((const char*)Bs + br * 128 + ((ks * 4 + g) ^ (br & 7)) * 16);
      }
#pragma unroll
      for (int mi = 0; mi < 4; ++mi)
#pragma unroll
        for (int ni = 0; ni < NI; ++ni)
          acc[mi][ni] = MFMA(af[mi], bfr[ni], acc[mi][ni]);
    }
    __syncthreads();
  }

  bf16* Cp; const float* bp; int colbase;
  if constexpr (EPI == 0) {
    const int seg = n0 >> 9;
    Cp = seg == 0 ? C0 : (seg == 1 ? C1 : C2);
    bp = seg == 0 ? b0 : (seg == 1 ? b1 : b2);
    colbase = n0 & 511;
  } else { Cp = C0; bp = b0; colbase = n0; }

#pragma unroll
  for (int ni = 0; ni < NI; ++ni) {
    const int col = colbase + wn + ni * 16 + c;
    const float bv = bp[col];
#pragma unroll
    for (int mi = 0; mi < 4; ++mi) {
#pragma unroll
      for (int r = 0; r < 4; ++r) {
        const int row = m0 + wm + mi * 16 + g * 4 + r;
        float v = acc[mi][ni][r] + bv;
        if constexpr (EPI == 1) v += rF[(size_t)row * Nout + col];
        if constexpr (EPI == 2) v = fmaxf(v, 0.f);
        if constexpr (EPI == 3) v += bf2f(rB[(size_t)row * Nout + col]);
        Cp[(size_t)row * Nout + col] = cvt_bf(v);
      }
    }
  }
}

// ---------------------------------------------------------------------------
// V transpose: V (per-bh [1024 k][64 d]) -> Vt per-bh [64 d][1024 k]
// ---------------------------------------------------------------------------
__global__ __launch_bounds__(256)
void vtr_k(const bf16* __restrict__ V, bf16* __restrict__ Vt)
{
  __shared__ bf16 tl[64][72];
  const int bh = blockIdx.y, kt = blockIdx.x;
  const int r = threadIdx.x >> 2, c = threadIdx.x & 3;
  const bf16* src = V + (size_t)bh * 65536 + (size_t)(kt * 64 + r) * 64 + c * 16;
  *(s16x8*)&tl[r][c * 16]     = *(const s16x8*)(src);
  *(s16x8*)&tl[r][c * 16 + 8] = *(const s16x8*)(src + 8);
  __syncthreads();
  union { bf16 h[8]; s16x8 v; } u0, u1;
#pragma unroll
  for (int j = 0; j < 8; ++j) { u0.h[j] = tl[c * 16 + j][r]; u1.h[j] = tl[c * 16 + 8 + j][r]; }
  bf16* dst = Vt + (size_t)bh * 65536 + (size_t)r * 1024 + kt * 64 + c * 16;
  *(s16x8*)dst = u0.v;
  *(s16x8*)(dst + 8) = u1.v;
}

// ---------------------------------------------------------------------------
// Attention v2 (register-resident P). See round-5 notes.
// ---------------------------------------------------------------------------
__global__ __launch_bounds__(256, 2)
void attn_k(const bf16* __restrict__ Q, const bf16* __restrict__ Kp,
            const bf16* __restrict__ Vt, const int* __restrict__ mask,
            bf16* __restrict__ ctx)
{
  __shared__ bf16 Ks[2][64 * 64];
  __shared__ bf16 Vs[2][64 * 64];
  __shared__ __align__(16) float koff[1024];
  const int lane = threadIdx.x & 63, wave = threadIdx.x >> 6;
  const int g = lane >> 4, c = lane & 15;
  const int wg = blockIdx.x;                   // 512 blocks
  const int swz = (wg & 7) * 64 + (wg >> 3);   // 8 consecutive bh per XCD
  const int qb = swz & 7, bh = swz >> 3;
  const int q0w = qb * 128 + wave * 32;
  const bf16* Qg = Q  + (size_t)bh * 65536;
  const bf16* Kg = Kp + (size_t)bh * 65536;
  const bf16* Vg = Vt + (size_t)bh * 65536;
  const int* mrow = mask + (bh & 7) * 1024;

  {
    const int i = threadIdx.x * 4;
    int4 m4 = *(const int4*)(mrow + i);
    f32x4 kv;
    kv[0] = m4.x ? 0.f : -1e30f;
    kv[1] = m4.y ? 0.f : -1e30f;
    kv[2] = m4.z ? 0.f : -1e30f;
    kv[3] = m4.w ? 0.f : -1e30f;
    *(f32x4*)&koff[i] = kv;
  }

  s16x8 qa[2][2];
#pragma unroll
  for (int qs = 0; qs < 2; ++qs)
#pragma unroll
    for (int h = 0; h < 2; ++h)
      qa[qs][h] = *(const s16x8*)(Qg + (size_t)(q0w + qs * 16 + c) * 64 + h * 32 + g * 8);

  float qm[2][4];
#pragma unroll
  for (int qs = 0; qs < 2; ++qs)
#pragma unroll
    for (int r = 0; r < 4; ++r)
      qm[qs][r] = mrow[q0w + qs * 16 + g * 4 + r] ? 1.f : 0.f;

  s16x8 ones;
#pragma unroll
  for (int i = 0; i < 8; ++i) ones[i] = (short)0x3F80;

  f32x4 acc[2][4], asum[2];
#pragma unroll
  for (int qs = 0; qs < 2; ++qs) {
    asum[qs] = (f32x4)0.f;
#pragma unroll
    for (int db = 0; db < 4; ++db) acc[qs][db] = (f32x4)0.f;
  }

  const int rl = lane >> 3, ch = lane & 7;
  const int schunk = (ch ^ rl) * 8;

  auto STAGE = [&](int kt, int buf) {
#pragma unroll
    for (int rnd = 0; rnd < 2; ++rnd) {
      const int rb = wave * 16 + rnd * 8;
      const int l = rb + rl;
      const int i16 = l & 15, kbb = l >> 4;
      const int srow = ((kbb >> 1) << 5) + ((i16 >> 2) << 3) + ((kbb & 1) << 2) + (i16 & 3);
      g2l16(Kg + (size_t)(kt * 64 + srow) * 64 + schunk, &Ks[buf][rb * 64]);
      g2l16(Vg + (size_t)l * 1024 + kt * 64 + schunk, &Vs[buf][rb * 64]);
    }
  };

  STAGE(0, 0);
  __syncthreads();

  for (int kt = 0; kt < 16; ++kt) {
    const int cur = kt & 1;
    if (kt < 15) STAGE(kt + 1, cur ^ 1);

    union { unsigned w[8]; s16x8 v[2]; } pr[2];

#pragma unroll
    for (int kb = 0; kb < 4; ++kb) {
      const int krow = kb * 16 + c;
      const char* kbase = (const char*)&Ks[cur][0] + krow * 128;
      const s16x8 kf0 = *(const s16x8*)(kbase + ((g    ) ^ (c & 7)) * 16);
      const s16x8 kf1 = *(const s16x8*)(kbase + ((g + 4) ^ (c & 7)) * 16);
      const f32x4 ko = *(const f32x4*)&koff[kt * 64 + ((kb >> 1) << 5) + (g << 3) + ((kb & 1) << 2)];
#pragma unroll
      for (int qs = 0; qs < 2; ++qs) {
        f32x4 z = (f32x4)0.f;
        z = MFMA(kf0, qa[qs][0], z);
        z = MFMA(kf1, qa[qs][1], z);
        union { bf16 h[4]; unsigned u[2]; } eh;
#pragma unroll
        for (int r = 0; r < 4; ++r)
          eh.h[r] = cvt_bf(__expf(fmaf(z[r], 0.125f, ko[r])));
        pr[qs].w[kb * 2]     = eh.u[0];
        pr[qs].w[kb * 2 + 1] = eh.u[1];
      }
    }

#pragma unroll
    for (int kk = 0; kk < 2; ++kk) {
      s16x8 vf[4];
#pragma unroll
      for (int db = 0; db < 4; ++db)
        vf[db] = *(const s16x8*)((const char*)&Vs[cur][0] + (db * 16 + c) * 128 + ((4 * kk + g) ^ (c & 7)) * 16);
#pragma unroll
      for (int qs = 0; qs < 2; ++qs) {
        const s16x8 pa = pr[qs].v[kk];
        asum[qs] = MFMA(pa, ones, asum[qs]);
#pragma unroll
        for (int db = 0; db < 4; ++db)
          acc[qs][db] = MFMA(pa, vf[db], acc[qs][db]);
      }
    }
    __syncthreads();
  }

#pragma unroll
  for (int qs = 0; qs < 2; ++qs)
#pragma unroll
    for (int r = 0; r < 4; ++r) {
      const float inv = qm[qs][r] / fmaxf(asum[qs][r], 1.f);
      const size_t qr = q0w + qs * 16 + g * 4 + r;
#pragma unroll
      for (int db = 0; db < 4; ++db)
        ctx[(size_t)bh * 65536 + qr * 64 + db * 16 + c] = cvt_bf(acc[qs][db][r] * inv);
    }
}

// ---------------------------------------------------------------------------
// LayerNorm D=512. 1 wave/row. INB: bf16 input; OUTF: f32 out; OUTB: bf16 out.
// ---------------------------------------------------------------------------
template<int INB, int OUTF, int OUTB>
__global__ __launch_bounds__(256)
void ln_k(const void* __restrict__ xin, const float* __restrict__ g,
          const float* __restrict__ bb, float* __restrict__ of, bf16* __restrict__ ob)
{
  const int row = blockIdx.x * 4 + (threadIdx.x >> 6);
  const int lane = threadIdx.x & 63;
  float xv[8];
  if constexpr (INB) {
    union { s16x8 v; bf16 h[8]; } u;
    u.v = *(const s16x8*)((const bf16*)xin + (size_t)row * 512 + lane * 8);
#pragma unroll
    for (int j = 0; j < 8; ++j) xv[j] = bf2f(u.h[j]);
  } else {
    const float* xr = (const float*)xin + (size_t)row * 512 + lane * 8;
    float4 a = *(const float4*)xr, b = *(const float4*)(xr + 4);
    xv[0]=a.x; xv[1]=a.y; xv[2]=a.z; xv[3]=a.w; xv[4]=b.x; xv[5]=b.y; xv[6]=b.z; xv[7]=b.w;
  }
  float s = 0.f, q = 0.f;
#pragma unroll
  for (int j = 0; j < 8; ++j) { s += xv[j]; q += xv[j] * xv[j]; }
#pragma unroll
  for (int m = 1; m < 64; m <<= 1) { s += __shfl_xor(s, m); q += __shfl_xor(q, m); }
  const float mu = s * (1.f / 512.f);
  const float var = q * (1.f / 512.f) - mu * mu;
  const float rs = rsqrtf(var + 1e-5f);
  float4 g0 = *(const float4*)(g + lane * 8),  g1 = *(const float4*)(g + lane * 8 + 4);
  float4 b0 = *(const float4*)(bb + lane * 8), b1 = *(const float4*)(bb + lane * 8 + 4);
  float gv[8] = {g0.x, g0.y, g0.z, g0.w, g1.x, g1.y, g1.z, g1.w};
  float bv[8] = {b0.x, b0.y, b0.z, b0.w, b1.x, b1.y, b1.z, b1.w};
  float ov[8];
#pragma unroll
  for (int j = 0; j < 8; ++j) ov[j] = (xv[j] - mu) * rs * gv[j] + bv[j];
  if constexpr (OUTF) {
    float4 o0 = {ov[0], ov[1], ov[2], ov[3]};
    float4 o1 = {ov[4], ov[5], ov[6], ov[7]};
    float* outr = of + (size_t)row * 512 + lane * 8;
    *(float4*)outr = o0;
    *(float4*)(outr + 4) = o1;
  }
  if constexpr (OUTB) {
    union { bf16 h[8]; s16x8 v; } u;
#pragma unroll
    for (int j = 0; j < 8; ++j) u.h[j] = cvt_bf(ov[j]);
    *(s16x8*)(ob + (size_t)row * 512 + lane * 8) = u.v;
  }
}

// ---------------------------------------------------------------------------
__global__ __launch_bounds__(256)
void mask_k(const int* __restrict__ m, float* __restrict__ out)
{
  const int i = blockIdx.x * 256 + threadIdx.x;
  const float v = (float)m[i];
  out[4194304 + i] = v;
  out[12591104 + i] = v;
}

// ---------------------------------------------------------------------------
extern "C" void kernel_launch(void* const* d_in, const int* in_sizes, int n_in,
                              void* d_out, int out_size, void* d_ws, size_t ws_size,
                              hipStream_t stream)
{
  const float* query = (const float*)d_in[0];
  const int*   qmask = (const int*)d_in[1];
  const float* wq = (const float*)d_in[2];
  const float* bq = (const float*)d_in[3];
  const float* wk = (const float*)d_in[4];
  const float* bk = (const float*)d_in[5];
  const float* wv = (const float*)d_in[6];
  const float* bv = (const float*)d_in[7];
  const float* wo = (const float*)d_in[8];
  const float* bo = (const float*)d_in[9];
  const float* ln1g = (const float*)d_in[10];
  const float* ln1b = (const float*)d_in[11];
  const float* w1 = (const float*)d_in[12];
  const float* b1 = (const float*)d_in[13];
  const float* w2 = (const float*)d_in[14];
  const float* b2 = (const float*)d_in[15];
  const float* ln2g = (const float*)d_in[16];
  const float* ln2b = (const float*)d_in[17];
  float* out = (float*)d_out;
  char* ws = (char*)d_ws;

  bf16* wqkvT = (bf16*)(ws);              // [1536][512]
  bf16* woT   = (bf16*)(ws + 1572864);    // [512][512]
  bf16* w1T   = (bf16*)(ws + 2097152);    // [1024][512]
  bf16* w2T   = (bf16*)(ws + 3145728);    // [512][1024]

  const dim3 blk(256);

  if (ws_size >= (size_t)96468992) {
    // ---------- big-workspace path: all scratch in d_ws, no aliasing ----------
    bf16*  qb    = (bf16*)(ws + 4194304);
    bf16*  Qb    = (bf16*)(ws + 12582912);
    bf16*  Kb    = (bf16*)(ws + 20971520);
    bf16*  Vb    = (bf16*)(ws + 29360128);
    bf16*  VtG   = (bf16*)(ws + 37748736);
    bf16*  ctx   = (bf16*)(ws + 46137344);
    bf16*  attnr = (bf16*)(ws + 54525952);
    bf16*  x1b   = (bf16*)(ws + 62914560);
    bf16*  hbuf  = (bf16*)(ws + 71303168);
    bf16*  ybuf  = (bf16*)(ws + 88080384);

    wcvt_all_k<<<2048, blk, 0, stream>>>(wq, wk, wv, wo, w1, w2, wqkvT, woT, w1T, w2T);
    prep_k<<<2080, blk, 0, stream>>>(query, qmask, qb, out);

    gemm_k<128, 0><<<768, blk, 0, stream>>>(qb, wqkvT, bq, bk, bv,
        nullptr, nullptr, Qb, Kb, Vb, 512, 512);
    vtr_k<<<dim3(16, 64), blk, 0, stream>>>(Vb, VtG);
    attn_k<<<512, blk, 0, stream>>>(Qb, Kb, VtG, qmask, ctx);
    gemm_k<64, 1><<<512, blk, 0, stream>>>(ctx, woT, bo, nullptr, nullptr,
        query, nullptr, attnr, nullptr, nullptr, 512, 512);
    ln_k<1, 0, 1><<<2048, blk, 0, stream>>>(attnr, ln1g, ln1b, nullptr, x1b);
    gemm_k<128, 2><<<512, blk, 0, stream>>>(x1b, w1T, b1, nullptr, nullptr,
        nullptr, nullptr, hbuf, nullptr, nullptr, 1024, 512);
    gemm_k<64, 3><<<512, blk, 0, stream>>>(hbuf, w2T, b2, nullptr, nullptr,
        nullptr, x1b, ybuf, nullptr, nullptr, 512, 1024);
    ln_k<1, 1, 0><<<2048, blk, 0, stream>>>(ybuf, ln2g, ln2b, out, nullptr);
  } else {
    // ---------- fallback: round-5 d_out-aliased layout ----------
    char* ob = (char*)d_out;
    char* R0 = ob;
    char* R1 = ob + 16809984;
    char* R2 = ob + 33587200;
    bf16*  qb    = (bf16*)R0;
    bf16*  ctx   = (bf16*)R0;
    bf16*  x1b   = (bf16*)R0;
    bf16*  Qb    = (bf16*)R1;
    bf16*  Kb    = (bf16*)(R1 + 8388608);
    bf16*  attnr = (bf16*)R1;
    bf16*  hbuf  = (bf16*)R1;
    bf16*  Vb    = (bf16*)R2;
    bf16*  VtG   = (bf16*)(R2 + 8388608);
    bf16*  ybuf  = (bf16*)R2;

    wcvt_all_k<<<2048, blk, 0, stream>>>(wq, wk, wv, wo, w1, w2, wqkvT, woT, w1T, w2T);
    cvt_k<<<2048, blk, 0, stream>>>(query, qb);
    gemm_k<128, 0><<<768, blk, 0, stream>>>(qb, wqkvT, bq, bk, bv,
        nullptr, nullptr, Qb, Kb, Vb, 512, 512);
    vtr_k<<<dim3(16, 64), blk, 0, stream>>>(Vb, VtG);
    attn_k<<<512, blk, 0, stream>>>(Qb, Kb, VtG, qmask, ctx);
    gemm_k<64, 1><<<512, blk, 0, stream>>>(ctx, woT, bo, nullptr, nullptr,
        query, nullptr, attnr, nullptr, nullptr, 512, 512);
    ln_k<1, 0, 1><<<2048, blk, 0, stream>>>(attnr, ln1g, ln1b, nullptr, x1b);
    gemm_k<128, 2><<<512, blk, 0, stream>>>(x1b, w1T, b1, nullptr, nullptr,
        nullptr, nullptr, hbuf, nullptr, nullptr, 1024, 512);
    gemm_k<64, 3><<<512, blk, 0, stream>>>(hbuf, w2T, b2, nullptr, nullptr,
        nullptr, x1b, ybuf, nullptr, nullptr, 512, 1024);
    ln_k<1, 1, 0><<<2048, blk, 0, stream>>>(ybuf, ln2g, ln2b, out, nullptr);
    mask_k<<<32, blk, 0, stream>>>(qmask, out);
    hipMemcpyAsync(out + 4202496, query, 16777216, hipMemcpyDeviceToDevice, stream);
    hipMemcpyAsync(out + 8396800, query, 16777216, hipMemcpyDeviceToDevice, stream);
  }
}

// Round 7
// 215.557 us; speedup vs baseline: 1.4292x; 1.0178x over previous
//
#include <hip/hip_runtime.h>
#include <hip/hip_bf16.h>

typedef __hip_bfloat16 bf16;
typedef __attribute__((ext_vector_type(4))) float f32x4;
typedef __attribute__((ext_vector_type(8))) short s16x8;
typedef __attribute__((ext_vector_type(4))) short s16x4;

#define MFMA(a, b, c) __builtin_amdgcn_mfma_f32_16x16x32_bf16((a), (b), (c), 0, 0, 0)

__device__ __forceinline__ void g2l16(const bf16* g, bf16* l) {
  __builtin_amdgcn_global_load_lds((const __attribute__((address_space(1))) void*)g,
                                   (__attribute__((address_space(3))) void*)l,
                                   16, 0, 0);
}
__device__ __forceinline__ bf16 cvt_bf(float f) { return __float2bfloat16(f); }
__device__ __forceinline__ float bf2f(bf16 h) { return __bfloat162float(h); }

// ---------------------------------------------------------------------------
// Fused prep: blocks 0-2047 weight transposes (f32 [K][N] -> bf16 [N][K]);
// blocks 2048-4095 query cvt + BOTH passthrough copies; 4096-4127 mask writes.
// ---------------------------------------------------------------------------
__global__ __launch_bounds__(256)
void prep2_k(const float* __restrict__ query, const int* __restrict__ qmask,
             const float* __restrict__ wq, const float* __restrict__ wk,
             const float* __restrict__ wv, const float* __restrict__ wo,
             const float* __restrict__ w1, const float* __restrict__ w2,
             bf16* __restrict__ wqkvT, bf16* __restrict__ woT,
             bf16* __restrict__ w1T, bf16* __restrict__ w2T,
             bf16* __restrict__ qb, float* __restrict__ out)
{
  __shared__ float tl[32][33];
  const int bid = blockIdx.x;
  if (bid < 2048) {
    const float* W; bf16* Wt; int K, N, tile;
    if (bid < 768)        { int s = bid >> 8; W = s==0?wq:(s==1?wk:wv);
                            Wt = wqkvT + s*262144; K = 512; N = 512; tile = bid & 255; }
    else if (bid < 1024)  { W = wo; Wt = woT; K = 512;  N = 512;  tile = bid - 768; }
    else if (bid < 1536)  { W = w1; Wt = w1T; K = 512;  N = 1024; tile = bid - 1024; }
    else                  { W = w2; Wt = w2T; K = 1024; N = 512;  tile = bid - 1536; }
    const int nx = N >> 5;
    const int n0 = (tile % nx) * 32, k0 = (tile / nx) * 32;
    const int tx = threadIdx.x & 31, ty = threadIdx.x >> 5;
#pragma unroll
    for (int i = 0; i < 32; i += 8)
      tl[ty + i][tx] = W[(size_t)(k0 + ty + i) * N + n0 + tx];
    __syncthreads();
#pragma unroll
    for (int i = 0; i < 32; i += 8)
      Wt[(size_t)(n0 + ty + i) * K + k0 + tx] = cvt_bf(tl[tx][ty + i]);
  } else if (bid < 4096) {
    const int i = (bid - 2048) * 2048 + threadIdx.x * 8;
    float4 a = *(const float4*)(query + i);
    float4 b = *(const float4*)(query + i + 4);
    union { bf16 h[8]; s16x8 v; } u;
    u.h[0] = cvt_bf(a.x); u.h[1] = cvt_bf(a.y); u.h[2] = cvt_bf(a.z); u.h[3] = cvt_bf(a.w);
    u.h[4] = cvt_bf(b.x); u.h[5] = cvt_bf(b.y); u.h[6] = cvt_bf(b.z); u.h[7] = cvt_bf(b.w);
    *(s16x8*)(qb + i) = u.v;
    float* o1 = out + 4202496 + i;
    float* o2 = out + 8396800 + i;
    *(float4*)o1 = a; *(float4*)(o1 + 4) = b;
    *(float4*)o2 = a; *(float4*)(o2 + 4) = b;
  } else {
    const int j = (bid - 4096) * 256 + threadIdx.x;  // 8192 total
    const float v = (float)qmask[j];
    out[4194304 + j] = v;
    out[12591104 + j] = v;
  }
}

// ---------------------------------------------------------------------------
// query f32 -> bf16 (fallback path only)
// ---------------------------------------------------------------------------
__global__ __launch_bounds__(256)
void cvt_k(const float* __restrict__ in, bf16* __restrict__ o)
{
  const int i = (blockIdx.x * 256 + threadIdx.x) * 8;
  float4 a = *(const float4*)(in + i);
  float4 b = *(const float4*)(in + i + 4);
  union { bf16 h[8]; s16x8 v; } u;
  u.h[0] = cvt_bf(a.x); u.h[1] = cvt_bf(a.y); u.h[2] = cvt_bf(a.z); u.h[3] = cvt_bf(a.w);
  u.h[4] = cvt_bf(b.x); u.h[5] = cvt_bf(b.y); u.h[6] = cvt_bf(b.z); u.h[7] = cvt_bf(b.w);
  *(s16x8*)(o + i) = u.v;
}

// ---------------------------------------------------------------------------
// Fallback-path weight transpose
// ---------------------------------------------------------------------------
__global__ __launch_bounds__(256)
void wcvt_all_k(const float* __restrict__ wq, const float* __restrict__ wk,
                const float* __restrict__ wv, const float* __restrict__ wo,
                const float* __restrict__ w1, const float* __restrict__ w2,
                bf16* __restrict__ wqkvT, bf16* __restrict__ woT,
                bf16* __restrict__ w1T, bf16* __restrict__ w2T)
{
  __shared__ float tl[32][33];
  const int bid = blockIdx.x;
  const float* W; bf16* Wt; int K, N, tile;
  if (bid < 768)        { int s = bid >> 8; W = s==0?wq:(s==1?wk:wv);
                          Wt = wqkvT + s*262144; K = 512; N = 512; tile = bid & 255; }
  else if (bid < 1024)  { W = wo; Wt = woT; K = 512;  N = 512;  tile = bid - 768; }
  else if (bid < 1536)  { W = w1; Wt = w1T; K = 512;  N = 1024; tile = bid - 1024; }
  else                  { W = w2; Wt = w2T; K = 1024; N = 512;  tile = bid - 1536; }
  const int nx = N >> 5;
  const int n0 = (tile % nx) * 32, k0 = (tile / nx) * 32;
  const int tx = threadIdx.x & 31, ty = threadIdx.x >> 5;
#pragma unroll
  for (int i = 0; i < 32; i += 8)
    tl[ty + i][tx] = W[(size_t)(k0 + ty + i) * N + n0 + tx];
  __syncthreads();
#pragma unroll
  for (int i = 0; i < 32; i += 8)
    Wt[(size_t)(n0 + ty + i) * K + k0 + tx] = cvt_bf(tl[tx][ty + i]);
}

// ---------------------------------------------------------------------------
// GEMM: C = A[8192][K] @ Bt[rows][K]^T, bf16 out. 128xBN tile, BK=64, 4 waves.
// SWAPPED accumulation (acc = MFMA(bfr, af)): lane's 4 acc values span 4
// consecutive OUTPUT COLUMNS -> packed 8B C-stores + vector bias/resid loads.
// 1D grid with XCD-chunked decode (8 m-tiles/XCD -> L2-resident panels).
// EPI 0: QKV merged; seg 2 (V) written TRANSPOSED per-bh [64 d][1024 k] (c
//        lanes cover 16 consecutive k -> 32B-coalesced scatter).
// EPI 1: +bias+f32 resid;  EPI 2: +bias+relu;  EPI 3: +bias+bf16 resid
// ---------------------------------------------------------------------------
template<int BN, int EPI>
__global__ __launch_bounds__(256, 2)
void gemm_k(const bf16* __restrict__ A, const bf16* __restrict__ Bt,
            const float* __restrict__ b0, const float* __restrict__ b1,
            const float* __restrict__ b2,
            const float* __restrict__ rF, const bf16* __restrict__ rB,
            bf16* __restrict__ C0, bf16* __restrict__ C1, bf16* __restrict__ C2,
            int Nout, int K)
{
  constexpr int NI = BN / 32;
  __shared__ bf16 As[128 * 64];
  __shared__ bf16 Bs[BN * 64];
  const int tid = threadIdx.x;
  const int wave = tid >> 6, lane = tid & 63;
  const int g = lane >> 4, c = lane & 15;
  const int wgid = blockIdx.x;
  const int xcd = wgid & 7, idx = wgid >> 3;
  const int m0 = (xcd * 8 + (idx & 7)) * 128;
  const int n0 = (idx >> 3) * BN;
  const int wm = (wave >> 1) * 64, wn = (wave & 1) * (BN / 2);
  const int srl = lane >> 3;
  const int csub = ((lane & 7) ^ (lane >> 3)) * 8;

  f32x4 acc[4][NI];
#pragma unroll
  for (int i = 0; i < 4; ++i)
#pragma unroll
    for (int j = 0; j < NI; ++j) acc[i][j] = (f32x4)0.f;

  for (int k0 = 0; k0 < K; k0 += 64) {
#pragma unroll
    for (int is = 0; is < 4; ++is) {
      const int tr = wave * 32 + is * 8;
      g2l16(A + (size_t)(m0 + tr + srl) * K + (k0 + csub), As + tr * 64);
    }
#pragma unroll
    for (int is = 0; is < BN / 32; ++is) {
      const int tr = wave * (BN / 4) + is * 8;
      g2l16(Bt + (size_t)(n0 + tr + srl) * K + (k0 + csub), Bs + tr * 64);
    }
    __syncthreads();
#pragma unroll
    for (int ks = 0; ks < 2; ++ks) {
      s16x8 af[4], bfr[NI];
#pragma unroll
      for (int i = 0; i < 4; ++i) {
        const int ar = wm + i * 16 + c;
        af[i] = *(const s16x8*)((const char*)As + ar * 128 + ((ks * 4 + g) ^ (ar & 7)) * 16);
      }
#pragma unroll
      for (int i = 0; i < NI; ++i) {
        const int br = wn + i * 16 + c;
        bfr[i] = *(const s16x8*)((const char*)Bs + br * 128 + ((ks * 4 + g) ^ (br & 7)) * 16);
      }
#pragma unroll
      for (int mi = 0; mi < 4; ++mi)
#pragma unroll
        for (int ni = 0; ni < NI; ++ni)
          acc[mi][ni] = MFMA(bfr[ni], af[mi], acc[mi][ni]);   // swapped: C'[n][m]
    }
    __syncthreads();
  }

  bf16* Cp; const float* bp; int colbase; int vseg = 0;
  if constexpr (EPI == 0) {
    const int seg = n0 >> 9;
    Cp = seg == 0 ? C0 : (seg == 1 ? C1 : C2);
    bp = seg == 0 ? b0 : (seg == 1 ? b1 : b2);
    colbase = n0 & 511;
    vseg = (seg == 2);
  } else { Cp = C0; bp = b0; colbase = n0; }

#pragma unroll
  for (int mi = 0; mi < 4; ++mi) {
    const int row = m0 + wm + mi * 16 + c;          // token index
#pragma unroll
    for (int ni = 0; ni < NI; ++ni) {
      const int colb = colbase + wn + ni * 16 + g * 4;  // 4 consecutive cols
      f32x4 v = acc[mi][ni];
      const f32x4 bv = *(const f32x4*)(bp + colb);
#pragma unroll
      for (int r = 0; r < 4; ++r) v[r] += bv[r];
      if constexpr (EPI == 1) {
        const f32x4 rv = *(const f32x4*)(rF + (size_t)row * Nout + colb);
#pragma unroll
        for (int r = 0; r < 4; ++r) v[r] += rv[r];
      }
      if constexpr (EPI == 2) {
#pragma unroll
        for (int r = 0; r < 4; ++r) v[r] = fmaxf(v[r], 0.f);
      }
      if constexpr (EPI == 3) {
        union { s16x4 x; bf16 h[4]; } rb;
        rb.x = *(const s16x4*)(rB + (size_t)row * Nout + colb);
#pragma unroll
        for (int r = 0; r < 4; ++r) v[r] += bf2f(rb.h[r]);
      }
      union { bf16 h[4]; s16x4 x; } o;
#pragma unroll
      for (int r = 0; r < 4; ++r) o.h[r] = cvt_bf(v[r]);
      if constexpr (EPI == 0) {
        if (vseg) {
          // transposed V write: Vt[bh][dd][k]
          const int bh = (row >> 10) * 8 + (colb >> 6);
          const int dd = colb & 63, kk2 = row & 1023;
          bf16* vp = Cp + (size_t)bh * 65536 + (size_t)dd * 1024 + kk2;
#pragma unroll
          for (int r = 0; r < 4; ++r) vp[r * 1024] = o.h[r];
        } else {
          *(s16x4*)(Cp + (size_t)row * Nout + colb) = o.x;
        }
      } else {
        *(s16x4*)(Cp + (size_t)row * Nout + colb) = o.x;
      }
    }
  }
}

// ---------------------------------------------------------------------------
// Attention v2 (register-resident P) — unchanged from round 5 (validated).
// ---------------------------------------------------------------------------
__global__ __launch_bounds__(256, 2)
void attn_k(const bf16* __restrict__ Q, const bf16* __restrict__ Kp,
            const bf16* __restrict__ Vt, const int* __restrict__ mask,
            bf16* __restrict__ ctx)
{
  __shared__ bf16 Ks[2][64 * 64];
  __shared__ bf16 Vs[2][64 * 64];
  __shared__ __align__(16) float koff[1024];
  const int lane = threadIdx.x & 63, wave = threadIdx.x >> 6;
  const int g = lane >> 4, c = lane & 15;
  const int wg = blockIdx.x;                   // 512 blocks
  const int swz = (wg & 7) * 64 + (wg >> 3);   // 8 consecutive bh per XCD
  const int qb = swz & 7, bh = swz >> 3;
  const int q0w = qb * 128 + wave * 32;
  const bf16* Qg = Q  + (size_t)bh * 65536;
  const bf16* Kg = Kp + (size_t)bh * 65536;
  const bf16* Vg = Vt + (size_t)bh * 65536;
  const int* mrow = mask + (bh & 7) * 1024;

  {
    const int i = threadIdx.x * 4;
    int4 m4 = *(const int4*)(mrow + i);
    f32x4 kv;
    kv[0] = m4.x ? 0.f : -1e30f;
    kv[1] = m4.y ? 0.f : -1e30f;
    kv[2] = m4.z ? 0.f : -1e30f;
    kv[3] = m4.w ? 0.f : -1e30f;
    *(f32x4*)&koff[i] = kv;
  }

  s16x8 qa[2][2];
#pragma unroll
  for (int qs = 0; qs < 2; ++qs)
#pragma unroll
    for (int h = 0; h < 2; ++h)
      qa[qs][h] = *(const s16x8*)(Qg + (size_t)(q0w + qs * 16 + c) * 64 + h * 32 + g * 8);

  float qm[2][4];
#pragma unroll
  for (int qs = 0; qs < 2; ++qs)
#pragma unroll
    for (int r = 0; r < 4; ++r)
      qm[qs][r] = mrow[q0w + qs * 16 + g * 4 + r] ? 1.f : 0.f;

  s16x8 ones;
#pragma unroll
  for (int i = 0; i < 8; ++i) ones[i] = (short)0x3F80;

  f32x4 acc[2][4], asum[2];
#pragma unroll
  for (int qs = 0; qs < 2; ++qs) {
    asum[qs] = (f32x4)0.f;
#pragma unroll
    for (int db = 0; db < 4; ++db) acc[qs][db] = (f32x4)0.f;
  }

  const int rl = lane >> 3, ch = lane & 7;
  const int schunk = (ch ^ rl) * 8;

  auto STAGE = [&](int kt, int buf) {
#pragma unroll
    for (int rnd = 0; rnd < 2; ++rnd) {
      const int rb = wave * 16 + rnd * 8;
      const int l = rb + rl;
      const int i16 = l & 15, kbb = l >> 4;
      const int srow = ((kbb >> 1) << 5) + ((i16 >> 2) << 3) + ((kbb & 1) << 2) + (i16 & 3);
      g2l16(Kg + (size_t)(kt * 64 + srow) * 64 + schunk, &Ks[buf][rb * 64]);
      g2l16(Vg + (size_t)l * 1024 + kt * 64 + schunk, &Vs[buf][rb * 64]);
    }
  };

  STAGE(0, 0);
  __syncthreads();

  for (int kt = 0; kt < 16; ++kt) {
    const int cur = kt & 1;
    if (kt < 15) STAGE(kt + 1, cur ^ 1);

    union { unsigned w[8]; s16x8 v[2]; } pr[2];

#pragma unroll
    for (int kb = 0; kb < 4; ++kb) {
      const int krow = kb * 16 + c;
      const char* kbase = (const char*)&Ks[cur][0] + krow * 128;
      const s16x8 kf0 = *(const s16x8*)(kbase + ((g    ) ^ (c & 7)) * 16);
      const s16x8 kf1 = *(const s16x8*)(kbase + ((g + 4) ^ (c & 7)) * 16);
      const f32x4 ko = *(const f32x4*)&koff[kt * 64 + ((kb >> 1) << 5) + (g << 3) + ((kb & 1) << 2)];
#pragma unroll
      for (int qs = 0; qs < 2; ++qs) {
        f32x4 z = (f32x4)0.f;
        z = MFMA(kf0, qa[qs][0], z);
        z = MFMA(kf1, qa[qs][1], z);
        union { bf16 h[4]; unsigned u[2]; } eh;
#pragma unroll
        for (int r = 0; r < 4; ++r)
          eh.h[r] = cvt_bf(__expf(fmaf(z[r], 0.125f, ko[r])));
        pr[qs].w[kb * 2]     = eh.u[0];
        pr[qs].w[kb * 2 + 1] = eh.u[1];
      }
    }

#pragma unroll
    for (int kk = 0; kk < 2; ++kk) {
      s16x8 vf[4];
#pragma unroll
      for (int db = 0; db < 4; ++db)
        vf[db] = *(const s16x8*)((const char*)&Vs[cur][0] + (db * 16 + c) * 128 + ((4 * kk + g) ^ (c & 7)) * 16);
#pragma unroll
      for (int qs = 0; qs < 2; ++qs) {
        const s16x8 pa = pr[qs].v[kk];
        asum[qs] = MFMA(pa, ones, asum[qs]);
#pragma unroll
        for (int db = 0; db < 4; ++db)
          acc[qs][db] = MFMA(pa, vf[db], acc[qs][db]);
      }
    }
    __syncthreads();
  }

#pragma unroll
  for (int qs = 0; qs < 2; ++qs)
#pragma unroll
    for (int r = 0; r < 4; ++r) {
      const float inv = qm[qs][r] / fmaxf(asum[qs][r], 1.f);
      const size_t qr = q0w + qs * 16 + g * 4 + r;
#pragma unroll
      for (int db = 0; db < 4; ++db)
        ctx[(size_t)bh * 65536 + qr * 64 + db * 16 + c] = cvt_bf(acc[qs][db][r] * inv);
    }
}

// ---------------------------------------------------------------------------
// LayerNorm D=512. 1 wave/row. INB: bf16 input; OUTF: f32 out; OUTB: bf16 out.
// ---------------------------------------------------------------------------
template<int INB, int OUTF, int OUTB>
__global__ __launch_bounds__(256)
void ln_k(const void* __restrict__ xin, const float* __restrict__ g,
          const float* __restrict__ bb, float* __restrict__ of, bf16* __restrict__ ob)
{
  const int row = blockIdx.x * 4 + (threadIdx.x >> 6);
  const int lane = threadIdx.x & 63;
  float xv[8];
  if constexpr (INB) {
    union { s16x8 v; bf16 h[8]; } u;
    u.v = *(const s16x8*)((const bf16*)xin + (size_t)row * 512 + lane * 8);
#pragma unroll
    for (int j = 0; j < 8; ++j) xv[j] = bf2f(u.h[j]);
  } else {
    const float* xr = (const float*)xin + (size_t)row * 512 + lane * 8;
    float4 a = *(const float4*)xr, b = *(const float4*)(xr + 4);
    xv[0]=a.x; xv[1]=a.y; xv[2]=a.z; xv[3]=a.w; xv[4]=b.x; xv[5]=b.y; xv[6]=b.z; xv[7]=b.w;
  }
  float s = 0.f, q = 0.f;
#pragma unroll
  for (int j = 0; j < 8; ++j) { s += xv[j]; q += xv[j] * xv[j]; }
#pragma unroll
  for (int m = 1; m < 64; m <<= 1) { s += __shfl_xor(s, m); q += __shfl_xor(q, m); }
  const float mu = s * (1.f / 512.f);
  const float var = q * (1.f / 512.f) - mu * mu;
  const float rs = rsqrtf(var + 1e-5f);
  float4 g0 = *(const float4*)(g + lane * 8),  g1 = *(const float4*)(g + lane * 8 + 4);
  float4 b0 = *(const float4*)(bb + lane * 8), b1 = *(const float4*)(bb + lane * 8 + 4);
  float gv[8] = {g0.x, g0.y, g0.z, g0.w, g1.x, g1.y, g1.z, g1.w};
  float bv[8] = {b0.x, b0.y, b0.z, b0.w, b1.x, b1.y, b1.z, b1.w};
  float ov[8];
#pragma unroll
  for (int j = 0; j < 8; ++j) ov[j] = (xv[j] - mu) * rs * gv[j] + bv[j];
  if constexpr (OUTF) {
    float4 o0 = {ov[0], ov[1], ov[2], ov[3]};
    float4 o1 = {ov[4], ov[5], ov[6], ov[7]};
    float* outr = of + (size_t)row * 512 + lane * 8;
    *(float4*)outr = o0;
    *(float4*)(outr + 4) = o1;
  }
  if constexpr (OUTB) {
    union { bf16 h[8]; s16x8 v; } u;
#pragma unroll
    for (int j = 0; j < 8; ++j) u.h[j] = cvt_bf(ov[j]);
    *(s16x8*)(ob + (size_t)row * 512 + lane * 8) = u.v;
  }
}

// ---------------------------------------------------------------------------
__global__ __launch_bounds__(256)
void mask_k(const int* __restrict__ m, float* __restrict__ out)
{
  const int i = blockIdx.x * 256 + threadIdx.x;
  const float v = (float)m[i];
  out[4194304 + i] = v;
  out[12591104 + i] = v;
}

// ---------------------------------------------------------------------------
extern "C" void kernel_launch(void* const* d_in, const int* in_sizes, int n_in,
                              void* d_out, int out_size, void* d_ws, size_t ws_size,
                              hipStream_t stream)
{
  const float* query = (const float*)d_in[0];
  const int*   qmask = (const int*)d_in[1];
  const float* wq = (const float*)d_in[2];
  const float* bq = (const float*)d_in[3];
  const float* wk = (const float*)d_in[4];
  const float* bk = (const float*)d_in[5];
  const float* wv = (const float*)d_in[6];
  const float* bv = (const float*)d_in[7];
  const float* wo = (const float*)d_in[8];
  const float* bo = (const float*)d_in[9];
  const float* ln1g = (const float*)d_in[10];
  const float* ln1b = (const float*)d_in[11];
  const float* w1 = (const float*)d_in[12];
  const float* b1 = (const float*)d_in[13];
  const float* w2 = (const float*)d_in[14];
  const float* b2 = (const float*)d_in[15];
  const float* ln2g = (const float*)d_in[16];
  const float* ln2b = (const float*)d_in[17];
  float* out = (float*)d_out;
  char* ws = (char*)d_ws;

  bf16* wqkvT = (bf16*)(ws);              // [1536][512]
  bf16* woT   = (bf16*)(ws + 1572864);    // [512][512]
  bf16* w1T   = (bf16*)(ws + 2097152);    // [1024][512]
  bf16* w2T   = (bf16*)(ws + 3145728);    // [512][1024]

  const dim3 blk(256);

  if (ws_size >= (size_t)96468992) {
    // ---------- big-workspace path ----------
    bf16*  qb    = (bf16*)(ws + 4194304);
    bf16*  Qb    = (bf16*)(ws + 12582912);
    bf16*  Kb    = (bf16*)(ws + 20971520);
    bf16*  VtG   = (bf16*)(ws + 37748736);
    bf16*  ctx   = (bf16*)(ws + 46137344);
    bf16*  attnr = (bf16*)(ws + 54525952);
    bf16*  x1b   = (bf16*)(ws + 62914560);
    bf16*  hbuf  = (bf16*)(ws + 71303168);
    bf16*  ybuf  = (bf16*)(ws + 88080384);

    prep2_k<<<4128, blk, 0, stream>>>(query, qmask, wq, wk, wv, wo, w1, w2,
                                      wqkvT, woT, w1T, w2T, qb, out);
    // QKV merged; V written transposed straight into VtG
    gemm_k<128, 0><<<768, blk, 0, stream>>>(qb, wqkvT, bq, bk, bv,
        nullptr, nullptr, Qb, Kb, VtG, 512, 512);
    attn_k<<<512, blk, 0, stream>>>(Qb, Kb, VtG, qmask, ctx);
    // out-proj + bf16 resid (qb)
    gemm_k<64, 3><<<512, blk, 0, stream>>>(ctx, woT, bo, nullptr, nullptr,
        nullptr, qb, attnr, nullptr, nullptr, 512, 512);
    ln_k<1, 0, 1><<<2048, blk, 0, stream>>>(attnr, ln1g, ln1b, nullptr, x1b);
    gemm_k<128, 2><<<512, blk, 0, stream>>>(x1b, w1T, b1, nullptr, nullptr,
        nullptr, nullptr, hbuf, nullptr, nullptr, 1024, 512);
    gemm_k<64, 3><<<512, blk, 0, stream>>>(hbuf, w2T, b2, nullptr, nullptr,
        nullptr, x1b, ybuf, nullptr, nullptr, 512, 1024);
    ln_k<1, 1, 0><<<2048, blk, 0, stream>>>(ybuf, ln2g, ln2b, out, nullptr);
  } else {
    // ---------- fallback: d_out-aliased scratch ----------
    char* ob = (char*)d_out;
    char* R0 = ob;
    char* R1 = ob + 16809984;
    char* R2 = ob + 33587200;
    bf16*  qb    = (bf16*)R0;
    bf16*  ctx   = (bf16*)R0;
    bf16*  x1b   = (bf16*)R0;
    bf16*  Qb    = (bf16*)R1;
    bf16*  Kb    = (bf16*)(R1 + 8388608);
    bf16*  attnr = (bf16*)R1;
    bf16*  hbuf  = (bf16*)R1;
    bf16*  VtG   = (bf16*)(R2 + 8388608);
    bf16*  ybuf  = (bf16*)R2;

    wcvt_all_k<<<2048, blk, 0, stream>>>(wq, wk, wv, wo, w1, w2, wqkvT, woT, w1T, w2T);
    cvt_k<<<2048, blk, 0, stream>>>(query, qb);
    gemm_k<128, 0><<<768, blk, 0, stream>>>(qb, wqkvT, bq, bk, bv,
        nullptr, nullptr, Qb, Kb, VtG, 512, 512);
    attn_k<<<512, blk, 0, stream>>>(Qb, Kb, VtG, qmask, ctx);
    // fallback keeps f32 query resid (qb overwritten by ctx here)
    gemm_k<64, 1><<<512, blk, 0, stream>>>(ctx, woT, bo, nullptr, nullptr,
        query, nullptr, attnr, nullptr, nullptr, 512, 512);
    ln_k<1, 0, 1><<<2048, blk, 0, stream>>>(attnr, ln1g, ln1b, nullptr, x1b);
    gemm_k<128, 2><<<512, blk, 0, stream>>>(x1b, w1T, b1, nullptr, nullptr,
        nullptr, nullptr, hbuf, nullptr, nullptr, 1024, 512);
    gemm_k<64, 3><<<512, blk, 0, stream>>>(hbuf, w2T, b2, nullptr, nullptr,
        nullptr, x1b, ybuf, nullptr, nullptr, 512, 1024);
    ln_k<1, 1, 0><<<2048, blk, 0, stream>>>(ybuf, ln2g, ln2b, out, nullptr);
    mask_k<<<32, blk, 0, stream>>>(qmask, out);
    hipMemcpyAsync(out + 4202496, query, 16777216, hipMemcpyDeviceToDevice, stream);
    hipMemcpyAsync(out + 8396800, query, 16777216, hipMemcpyDeviceToDevice, stream);
  }
}